// Round 9
// baseline (9400.710 us; speedup 1.0000x reference)
//
#include <hip/hip_runtime.h>
#include <hip/hip_fp16.h>
#include <math.h>

#define SELU_SCALE 1.0507009873554805f
#define SELU_ALPHA 1.6732632423543772f

static inline int cdiv(long long a, int b) { return (int)((a + b - 1) / b); }

// packed fp16 max (v_pk_max_f16) — __hmax2 intrinsic is missing on this ROCm
__device__ __forceinline__ __half2 hmax2(__half2 a, __half2 b) {
    __half2 r;
    asm("v_pk_max_f16 %0, %1, %2" : "=v"(r) : "v"(a), "v"(b));
    return r;
}

// ===================== edge preprocessing =====================

__global__ void zero_int_kernel(int* __restrict__ p, int n) {
    int i = blockIdx.x * blockDim.x + threadIdx.x;
    if (i < n) p[i] = 0;
}

__global__ void hist4_kernel(const int* __restrict__ dst, int* __restrict__ cnt, int E) {
    int i = blockIdx.x * blockDim.x + threadIdx.x;
    int base = i * 4;
    if (base + 3 < E) {
        int4 d = *reinterpret_cast<const int4*>(dst + base);
        atomicAdd(&cnt[d.x], 1);
        atomicAdd(&cnt[d.y], 1);
        atomicAdd(&cnt[d.z], 1);
        atomicAdd(&cnt[d.w], 1);
    } else {
        for (int e = base; e < E; ++e) atomicAdd(&cnt[dst[e]], 1);
    }
}

__global__ void dinv_kernel(const int* __restrict__ cnt, float* __restrict__ dinv, int N) {
    int i = blockIdx.x * blockDim.x + threadIdx.x;
    if (i < N) dinv[i] = rsqrtf((float)cnt[i] + 1.0f);  // +1 self loop
}

__global__ void scan_partial_kernel(const int* __restrict__ cnt, int* __restrict__ bsum, int N) {
    __shared__ int sh[256];
    int base = blockIdx.x * 1024;
    int t = threadIdx.x;
    int s = 0;
#pragma unroll
    for (int k = 0; k < 4; ++k) {
        int i = base + t * 4 + k;
        if (i < N) s += cnt[i];
    }
    sh[t] = s;
    __syncthreads();
    for (int o = 128; o > 0; o >>= 1) {
        if (t < o) sh[t] += sh[t + o];
        __syncthreads();
    }
    if (t == 0) bsum[blockIdx.x] = sh[0];
}

__global__ void scan_bsum_par_kernel(int* __restrict__ bsum, int nb) {
    __shared__ int sh[1024];
    int t = threadIdx.x;
    int v = (t < nb) ? bsum[t] : 0;
    sh[t] = v;
    __syncthreads();
    for (int o = 1; o < 1024; o <<= 1) {
        int y = (t >= o) ? sh[t - o] : 0;
        __syncthreads();
        sh[t] += y;
        __syncthreads();
    }
    if (t < nb) bsum[t] = sh[t] - v;
}

__global__ void scan_bsum_serial_kernel(int* __restrict__ bsum, int nb) {
    if (blockIdx.x == 0 && threadIdx.x == 0) {
        int acc = 0;
        for (int i = 0; i < nb; ++i) { int v = bsum[i]; bsum[i] = acc; acc += v; }
    }
}

__global__ void scan_final_kernel(const int* __restrict__ cnt, const int* __restrict__ bsum,
                                  int* __restrict__ row_ptr, int N, int E) {
    __shared__ int sh[256];
    int base = blockIdx.x * 1024;
    int t = threadIdx.x;
    int i0 = base + t * 4;
    int v0 = (i0 + 0 < N) ? cnt[i0 + 0] : 0;
    int v1 = (i0 + 1 < N) ? cnt[i0 + 1] : 0;
    int v2 = (i0 + 2 < N) ? cnt[i0 + 2] : 0;
    int v3 = (i0 + 3 < N) ? cnt[i0 + 3] : 0;
    sh[t] = v0 + v1 + v2 + v3;
    __syncthreads();
    for (int o = 1; o < 256; o <<= 1) {
        int y = (t >= o) ? sh[t - o] : 0;
        __syncthreads();
        sh[t] += y;
        __syncthreads();
    }
    int off = bsum[blockIdx.x] + ((t > 0) ? sh[t - 1] : 0);
    if (i0 + 0 < N) row_ptr[i0 + 0] = off;  off += v0;
    if (i0 + 1 < N) row_ptr[i0 + 1] = off;  off += v1;
    if (i0 + 2 < N) row_ptr[i0 + 2] = off;  off += v2;
    if (i0 + 3 < N) row_ptr[i0 + 3] = off;
    if (blockIdx.x == 0 && t == 0) row_ptr[N] = E;
}

__global__ void fill_sorted4_kernel(const int* __restrict__ src, const int* __restrict__ dst,
                                    const int* __restrict__ row_ptr, int* __restrict__ cursor,
                                    int* __restrict__ sorted_src, int E) {
    int i = blockIdx.x * blockDim.x + threadIdx.x;
    int base = i * 4;
    if (base + 3 < E) {
        int4 d = *reinterpret_cast<const int4*>(dst + base);
        int4 s = *reinterpret_cast<const int4*>(src + base);
        int r0 = row_ptr[d.x];
        int r1 = row_ptr[d.y];
        int r2 = row_ptr[d.z];
        int r3 = row_ptr[d.w];
        int k0 = atomicAdd(&cursor[d.x], 1);
        int k1 = atomicAdd(&cursor[d.y], 1);
        int k2 = atomicAdd(&cursor[d.z], 1);
        int k3 = atomicAdd(&cursor[d.w], 1);
        sorted_src[r0 + k0] = s.x;
        sorted_src[r1 + k1] = s.y;
        sorted_src[r2 + k2] = s.z;
        sorted_src[r3 + k3] = s.w;
    } else {
        for (int e = base; e < E; ++e) {
            int dd = dst[e];
            int pos = row_ptr[dd] + atomicAdd(&cursor[dd], 1);
            sorted_src[pos] = src[e];
        }
    }
}

// ===================== degree-binned node permutation =====================
// Lanes of a wave get equal-degree nodes -> serial gather depth = own degree,
// not max over 64 lanes (tail removal; results identical).

#define DBINS 64

__global__ void degbin_hist_kernel(const int* __restrict__ row_ptr, int* __restrict__ bins, int N) {
    int n = blockIdx.x * blockDim.x + threadIdx.x;
    if (n >= N) return;
    int d = row_ptr[n + 1] - row_ptr[n];
    int b = (d < DBINS) ? d : (DBINS - 1);
    atomicAdd(&bins[b], 1);
}

__global__ void degbin_scan_kernel(const int* __restrict__ bins, int* __restrict__ cursor) {
    // single wave: exclusive scan of 64 bins
    if (threadIdx.x == 0 && blockIdx.x == 0) {
        int acc = 0;
        for (int i = 0; i < DBINS; ++i) { int v = bins[i]; cursor[i] = acc; acc += v; }
    }
}

__global__ void degbin_scatter_kernel(const int* __restrict__ row_ptr, int* __restrict__ cursor,
                                      int* __restrict__ perm, int N) {
    int n = blockIdx.x * blockDim.x + threadIdx.x;
    if (n >= N) return;
    int d = row_ptr[n + 1] - row_ptr[n];
    int b = (d < DBINS) ? d : (DBINS - 1);
    int p = atomicAdd(&cursor[b], 1);
    perm[p] = n;
}

// ===================== fp16 row helpers (packed half2) =====================

template <int SH>
__device__ __forceinline__ void load_row_h2(__half2* __restrict__ acc, const __half* __restrict__ row) {
#pragma unroll
    for (int u = 0; u < SH / 8; ++u) {
        union { float4 f4; __half2 h2[4]; } ld;
        ld.f4 = *reinterpret_cast<const float4*>(row + u * 8);
#pragma unroll
        for (int k = 0; k < 4; ++k) acc[u * 4 + k] = ld.h2[k];
    }
}

template <int SH>
__device__ __forceinline__ void fmax_row_h2(__half2* __restrict__ acc, const __half* __restrict__ row) {
#pragma unroll
    for (int u = 0; u < SH / 8; ++u) {
        union { float4 f4; __half2 h2[4]; } ld;
        ld.f4 = *reinterpret_cast<const float4*>(row + u * 8);
#pragma unroll
        for (int k = 0; k < 4; ++k) acc[u * 4 + k] = hmax2(acc[u * 4 + k], ld.h2[k]);
    }
}

template <int FOUT, int SOUTH>
__device__ __forceinline__ void store_row_h(__half* __restrict__ op,
                                            const float* __restrict__ vals, float dv) {
#pragma unroll
    for (int u = 0; u < SOUTH / 8; ++u) {
        union { float4 f4; __half2 h2[4]; } pk;
#pragma unroll
        for (int k = 0; k < 4; ++k) {
            int f0 = u * 8 + 2 * k, f1 = f0 + 1;
            float a = (f0 < FOUT) ? vals[(f0 < FOUT) ? f0 : 0] * dv : 0.0f;
            float b = (f1 < FOUT) ? vals[(f1 < FOUT) ? f1 : 0] * dv : 0.0f;
            pk.h2[k] = __floats2half2_rn(a, b);
        }
        *reinterpret_cast<float4*>(op + u * 8) = pk.f4;
    }
}

// neighbor max loop, unroll-4 (4 independent row loads in flight)
template <int SH>
__device__ __forceinline__ void gather_max_loop(__half2* __restrict__ acc,
                                                const __half* __restrict__ u,
                                                const int* __restrict__ sorted_src,
                                                int j0, int j1) {
    int j = j0;
    for (; j + 4 <= j1; j += 4) {
        int s0 = sorted_src[j + 0];
        int s1 = sorted_src[j + 1];
        int s2 = sorted_src[j + 2];
        int s3 = sorted_src[j + 3];
        fmax_row_h2<SH>(acc, u + (long long)s0 * SH);
        fmax_row_h2<SH>(acc, u + (long long)s1 * SH);
        fmax_row_h2<SH>(acc, u + (long long)s2 * SH);
        fmax_row_h2<SH>(acc, u + (long long)s3 * SH);
    }
    for (; j < j1; ++j) fmax_row_h2<SH>(acc, u + (long long)sorted_src[j] * SH);
}

// ===================== layer kernels =====================

// layer-1 GEMM: u1[n,:] = half((x[n,:] @ W1) * dinv[n])
template <int FIN, int FOUT, int SOUTH>
__global__ void gemm_scale_kernel(const float* __restrict__ h,
                                  const float* __restrict__ W,
                                  const float* __restrict__ dinv,
                                  __half* __restrict__ u,
                                  int N) {
    int n = blockIdx.x * blockDim.x + threadIdx.x;
    if (n >= N) return;
    const float* hr = h + (long long)n * FIN;
    float acc[FOUT];
#pragma unroll
    for (int c = 0; c < FOUT; ++c) acc[c] = 0.0f;
#pragma unroll
    for (int fi = 0; fi < FIN; ++fi) {
        float hv = hr[fi];
#pragma unroll
        for (int c = 0; c < FOUT; ++c) acc[c] += hv * W[fi * FOUT + c];
    }
    store_row_h<FOUT, SOUTH>(u + (long long)n * SOUTH, acc, dinv[n]);
}

// fused agg + next-layer GEMM, thread per node (degree-permuted)
template <int SPREVH, int FPREV, int FOUT, int SOUTH>
__global__ void agg_gemm_kernel(const __half* __restrict__ u,
                                const int* __restrict__ row_ptr,
                                const int* __restrict__ sorted_src,
                                const int* __restrict__ perm,
                                const float* __restrict__ dinv,
                                const float* __restrict__ bprev,
                                const float* __restrict__ W,
                                __half* __restrict__ uout,
                                int N) {
    int gid = blockIdx.x * blockDim.x + threadIdx.x;
    if (gid >= N) return;
    int n = perm[gid];
    __half2 acc[SPREVH / 2];
    load_row_h2<SPREVH>(acc, u + (long long)n * SPREVH);  // self loop
    int j0 = row_ptr[n], j1 = row_ptr[n + 1];
    gather_max_loop<SPREVH>(acc, u, sorted_src, j0, j1);

    float af[SPREVH];
#pragma unroll
    for (int i = 0; i < SPREVH / 2; ++i) {
        float2 p = __half22float2(acc[i]);
        af[2 * i] = p.x;
        af[2 * i + 1] = p.y;
    }
    float dv = dinv[n];
    float h[FPREV];
#pragma unroll
    for (int f = 0; f < FPREV; ++f) {
        float v = dv * af[f] + bprev[f];
        h[f] = (v > 0.0f) ? (SELU_SCALE * v) : (SELU_SCALE * SELU_ALPHA * (expf(v) - 1.0f));
    }
    float outv[FOUT];
#pragma unroll
    for (int c = 0; c < FOUT; ++c) outv[c] = 0.0f;
#pragma unroll
    for (int fi = 0; fi < FPREV; ++fi) {
        float hv = h[fi];
#pragma unroll
        for (int c = 0; c < FOUT; ++c) outv[c] += hv * W[fi * FOUT + c];
    }
    store_row_h<FOUT, SOUTH>(uout + (long long)n * SOUTH, outv, dv);
}

// final aggregation (layer 4): fp32 output stride F, thread per node (permuted)
template <int SH, int F>
__global__ void agg_selu_kernel(const __half* __restrict__ u,
                                const int* __restrict__ row_ptr,
                                const int* __restrict__ sorted_src,
                                const int* __restrict__ perm,
                                const float* __restrict__ dinv,
                                const float* __restrict__ b,
                                float* __restrict__ hout,
                                int N) {
    int gid = blockIdx.x * blockDim.x + threadIdx.x;
    if (gid >= N) return;
    int n = perm[gid];
    __half2 acc[SH / 2];
    load_row_h2<SH>(acc, u + (long long)n * SH);
    int j0 = row_ptr[n], j1 = row_ptr[n + 1];
    gather_max_loop<SH>(acc, u, sorted_src, j0, j1);

    float dv = dinv[n];
    float* op = hout + (long long)n * F;
#pragma unroll
    for (int q = 0; q < F / 4; ++q) {
        float4 o;
        float* ov = &o.x;
#pragma unroll
        for (int k = 0; k < 4; ++k) {
            int f = 4 * q + k;
            float2 p = __half22float2(acc[f / 2]);
            float raw = (f & 1) ? p.y : p.x;
            float v = dv * raw + b[f];
            ov[k] = (v > 0.0f) ? (SELU_SCALE * v) : (SELU_SCALE * SELU_ALPHA * (expf(v) - 1.0f));
        }
        *reinterpret_cast<float4*>(op + 4 * q) = o;
    }
}

// ===================== pooling =====================

__global__ void segstart_kernel(const int* __restrict__ batch, int* __restrict__ seg, int N, int G) {
    int g = blockIdx.x * blockDim.x + threadIdx.x;
    if (g > G) return;
    if (g == G) { seg[G] = N; return; }
    int lo = 0, hi = N;
    while (lo < hi) { int mid = (lo + hi) >> 1; if (batch[mid] < g) lo = mid + 1; else hi = mid; }
    seg[g] = lo;
}

__global__ void pool_kernel(const float* __restrict__ h,
                            const int* __restrict__ seg,
                            float* __restrict__ pooled,
                            int G) {
    int idx = blockIdx.x * blockDim.x + threadIdx.x;  // G * 9
    if (idx >= G * 9) return;
    int g = idx / 9;
    int t = idx - g * 9;
    int lo = seg[g], hi = seg[g + 1];
    float4 acc = make_float4(0.f, 0.f, 0.f, 0.f);
    for (int n = lo; n < hi; ++n) {
        float4 v = *reinterpret_cast<const float4*>(h + (long long)n * 36 + 4 * t);
        acc.x += v.x; acc.y += v.y; acc.z += v.z; acc.w += v.w;
    }
    *reinterpret_cast<float4*>(pooled + (long long)g * 36 + 4 * t) = acc;
}

// ===================== MLP head =====================

__global__ void mlp1_kernel(const float* __restrict__ pooled,
                            const float* __restrict__ lw1,
                            const float* __restrict__ lb1,
                            float* __restrict__ y1,
                            int G) {
    __shared__ float Ws[36 * 96];
    for (int i = threadIdx.x; i < 36 * 96; i += blockDim.x) Ws[i] = lw1[i];
    __syncthreads();
    int idx = blockIdx.x * blockDim.x + threadIdx.x;
    if (idx >= G * 96) return;
    int g = idx / 96;
    int j = idx - g * 96;
    const float* pr = pooled + (long long)g * 36;
    float acc = lb1[j];
#pragma unroll
    for (int k4 = 0; k4 < 9; ++k4) {
        float4 pv = *reinterpret_cast<const float4*>(pr + 4 * k4);
        acc += pv.x * Ws[(4 * k4 + 0) * 96 + j];
        acc += pv.y * Ws[(4 * k4 + 1) * 96 + j];
        acc += pv.z * Ws[(4 * k4 + 2) * 96 + j];
        acc += pv.w * Ws[(4 * k4 + 3) * 96 + j];
    }
    y1[idx] = fmaxf(acc, 0.0f);
}

__global__ void mlp2_kernel(const float* __restrict__ y1,
                            const float* __restrict__ lw2,
                            const float* __restrict__ lb2,
                            float* __restrict__ out,
                            int G) {
    __shared__ float Ws[96 * 27];
    for (int i = threadIdx.x; i < 96 * 27; i += blockDim.x) Ws[i] = lw2[i];
    __syncthreads();
    int idx = blockIdx.x * blockDim.x + threadIdx.x;
    if (idx >= G * 27) return;
    int g = idx / 27;
    int c = idx - g * 27;
    const float* yr = y1 + (long long)g * 96;
    float acc = lb2[c];
#pragma unroll
    for (int k4 = 0; k4 < 24; ++k4) {
        float4 yv = *reinterpret_cast<const float4*>(yr + 4 * k4);
        acc += yv.x * Ws[(4 * k4 + 0) * 27 + c];
        acc += yv.y * Ws[(4 * k4 + 1) * 27 + c];
        acc += yv.z * Ws[(4 * k4 + 2) * 27 + c];
        acc += yv.w * Ws[(4 * k4 + 3) * 27 + c];
    }
    out[idx] = fmaxf(acc, 0.0f);
}

// ===================== launch =====================

extern "C" void kernel_launch(void* const* d_in, const int* in_sizes, int n_in,
                              void* d_out, int out_size, void* d_ws, size_t ws_size,
                              hipStream_t stream) {
    const float* x     = (const float*)d_in[0];
    const int*   ei    = (const int*)d_in[1];
    const int*   batch = (const int*)d_in[2];
    const float* W1  = (const float*)d_in[4];
    const float* b1  = (const float*)d_in[5];
    const float* W2  = (const float*)d_in[6];
    const float* b2  = (const float*)d_in[7];
    const float* W3  = (const float*)d_in[8];
    const float* b3  = (const float*)d_in[9];
    const float* W4  = (const float*)d_in[10];
    const float* b4  = (const float*)d_in[11];
    const float* lw1 = (const float*)d_in[12];
    const float* lb1 = (const float*)d_in[13];
    const float* lw2 = (const float*)d_in[14];
    const float* lb2 = (const float*)d_in[15];
    float* out = (float*)d_out;

    const int N = in_sizes[0] / 75;
    const int E = in_sizes[1] / 2;
    const int G = out_size / 27;
    const int* srcp = ei;
    const int* dstp = ei + E;

    char* ws = (char*)d_ws;
    size_t off = 0;
    auto carve = [&](size_t bytes) -> char* {
        char* p = ws + off;
        off = (off + bytes + 255) & ~(size_t)255;
        return p;
    };
    int*    cnt        = (int*)carve((size_t)N * 4);
    int*    row_ptr    = (int*)carve((size_t)(N + 1) * 4);
    int*    sorted_src = (int*)carve((size_t)E * 4);
    int*    bsum       = (int*)carve((size_t)cdiv(N, 1024) * 4 + 4);
    int*    seg        = (int*)carve((size_t)(G + 1) * 4);
    int*    perm       = (int*)carve((size_t)N * 4);
    int*    dbins      = (int*)carve((size_t)DBINS * 4);
    int*    dcursor    = (int*)carve((size_t)DBINS * 4);
    float*  dinv       = (float*)carve((size_t)N * 4);
    char*   Abuf       = carve((size_t)N * 36 * 4);
    char*   Bbuf       = carve((size_t)N * 36 * 4);
    float*  pooled     = (float*)carve((size_t)G * 36 * 4);
    float*  y1         = (float*)carve((size_t)G * 96 * 4);
    (void)ws_size; (void)n_in;

    const int BLK = 256;
    const int nb = cdiv(N, 1024);

    // ---- edge preprocessing ----
    zero_int_kernel<<<cdiv(N, BLK), BLK, 0, stream>>>(cnt, N);
    hist4_kernel<<<cdiv(cdiv(E, 4), BLK), BLK, 0, stream>>>(dstp, cnt, E);
    dinv_kernel<<<cdiv(N, BLK), BLK, 0, stream>>>(cnt, dinv, N);
    scan_partial_kernel<<<nb, 256, 0, stream>>>(cnt, bsum, N);
    if (nb <= 1024) scan_bsum_par_kernel<<<1, 1024, 0, stream>>>(bsum, nb);
    else            scan_bsum_serial_kernel<<<1, 64, 0, stream>>>(bsum, nb);
    scan_final_kernel<<<nb, 256, 0, stream>>>(cnt, bsum, row_ptr, N, E);
    zero_int_kernel<<<cdiv(N, BLK), BLK, 0, stream>>>(cnt, N);  // cursor = 0
    fill_sorted4_kernel<<<cdiv(cdiv(E, 4), BLK), BLK, 0, stream>>>(srcp, dstp, row_ptr, cnt, sorted_src, E);
    segstart_kernel<<<cdiv(G + 1, BLK), BLK, 0, stream>>>(batch, seg, N, G);

    // ---- degree-binned permutation (tail removal for agg kernels) ----
    zero_int_kernel<<<1, DBINS, 0, stream>>>(dbins, DBINS);
    degbin_hist_kernel<<<cdiv(N, BLK), BLK, 0, stream>>>(row_ptr, dbins, N);
    degbin_scan_kernel<<<1, 64, 0, stream>>>(dbins, dcursor);
    degbin_scatter_kernel<<<cdiv(N, BLK), BLK, 0, stream>>>(row_ptr, dcursor, perm, N);

    // fp16 u strides (halves): u1=16 (32B), u2=32 (64B line), u3=32 (64B line), u4=40 (80B)
    __half* u1 = (__half*)Bbuf;
    __half* u2 = (__half*)Abuf;
    __half* u3 = (__half*)Bbuf;
    __half* u4 = (__half*)Abuf;
    float*  h4 = (float*)Bbuf;

    gemm_scale_kernel<75, 15, 16><<<cdiv(N, BLK), BLK, 0, stream>>>(x, W1, dinv, u1, N);
    agg_gemm_kernel<16, 15, 20, 32><<<cdiv(N, BLK), BLK, 0, stream>>>(u1, row_ptr, sorted_src, perm, dinv, b1, W2, u2, N);
    agg_gemm_kernel<32, 20, 27, 32><<<cdiv(N, BLK), BLK, 0, stream>>>(u2, row_ptr, sorted_src, perm, dinv, b2, W3, u3, N);
    agg_gemm_kernel<32, 27, 36, 40><<<cdiv(N, BLK), BLK, 0, stream>>>(u3, row_ptr, sorted_src, perm, dinv, b3, W4, u4, N);
    agg_selu_kernel<40, 36><<<cdiv(N, BLK), BLK, 0, stream>>>(u4, row_ptr, sorted_src, perm, dinv, b4, h4, N);

    // ---- pool: segmented sum (batch_vec is sorted) ----
    pool_kernel<<<cdiv((long long)G * 9, BLK), BLK, 0, stream>>>(h4, seg, pooled, G);

    // ---- MLP head ----
    mlp1_kernel<<<cdiv((long long)G * 96, BLK), BLK, 0, stream>>>(pooled, lw1, lb1, y1, G);
    mlp2_kernel<<<cdiv((long long)G * 27, BLK), BLK, 0, stream>>>(y1, lw2, lb2, out, G);
}

// Round 10
// 1342.701 us; speedup vs baseline: 7.0013x; 7.0013x over previous
//
#include <hip/hip_runtime.h>
#include <hip/hip_fp16.h>
#include <math.h>

#define SELU_SCALE 1.0507009873554805f
#define SELU_ALPHA 1.6732632423543772f

static inline int cdiv(long long a, int b) { return (int)((a + b - 1) / b); }

// packed fp16 max (v_pk_max_f16) — __hmax2 intrinsic is missing on this ROCm
__device__ __forceinline__ __half2 hmax2(__half2 a, __half2 b) {
    __half2 r;
    asm("v_pk_max_f16 %0, %1, %2" : "=v"(r) : "v"(a), "v"(b));
    return r;
}

// ===================== edge preprocessing =====================

__global__ void zero_int_kernel(int* __restrict__ p, int n) {
    int i = blockIdx.x * blockDim.x + threadIdx.x;
    if (i < n) p[i] = 0;
}

__global__ void hist4_kernel(const int* __restrict__ dst, int* __restrict__ cnt, int E) {
    int i = blockIdx.x * blockDim.x + threadIdx.x;
    int base = i * 4;
    if (base + 3 < E) {
        int4 d = *reinterpret_cast<const int4*>(dst + base);
        atomicAdd(&cnt[d.x], 1);
        atomicAdd(&cnt[d.y], 1);
        atomicAdd(&cnt[d.z], 1);
        atomicAdd(&cnt[d.w], 1);
    } else {
        for (int e = base; e < E; ++e) atomicAdd(&cnt[dst[e]], 1);
    }
}

__global__ void dinv_kernel(const int* __restrict__ cnt, float* __restrict__ dinv, int N) {
    int i = blockIdx.x * blockDim.x + threadIdx.x;
    if (i < N) dinv[i] = rsqrtf((float)cnt[i] + 1.0f);  // +1 self loop
}

__global__ void scan_partial_kernel(const int* __restrict__ cnt, int* __restrict__ bsum, int N) {
    __shared__ int sh[256];
    int base = blockIdx.x * 1024;
    int t = threadIdx.x;
    int s = 0;
#pragma unroll
    for (int k = 0; k < 4; ++k) {
        int i = base + t * 4 + k;
        if (i < N) s += cnt[i];
    }
    sh[t] = s;
    __syncthreads();
    for (int o = 128; o > 0; o >>= 1) {
        if (t < o) sh[t] += sh[t + o];
        __syncthreads();
    }
    if (t == 0) bsum[blockIdx.x] = sh[0];
}

__global__ void scan_bsum_par_kernel(int* __restrict__ bsum, int nb) {
    __shared__ int sh[1024];
    int t = threadIdx.x;
    int v = (t < nb) ? bsum[t] : 0;
    sh[t] = v;
    __syncthreads();
    for (int o = 1; o < 1024; o <<= 1) {
        int y = (t >= o) ? sh[t - o] : 0;
        __syncthreads();
        sh[t] += y;
        __syncthreads();
    }
    if (t < nb) bsum[t] = sh[t] - v;
}

__global__ void scan_bsum_serial_kernel(int* __restrict__ bsum, int nb) {
    if (blockIdx.x == 0 && threadIdx.x == 0) {
        int acc = 0;
        for (int i = 0; i < nb; ++i) { int v = bsum[i]; bsum[i] = acc; acc += v; }
    }
}

__global__ void scan_final_kernel(const int* __restrict__ cnt, const int* __restrict__ bsum,
                                  int* __restrict__ row_ptr, int N, int E) {
    __shared__ int sh[256];
    int base = blockIdx.x * 1024;
    int t = threadIdx.x;
    int i0 = base + t * 4;
    int v0 = (i0 + 0 < N) ? cnt[i0 + 0] : 0;
    int v1 = (i0 + 1 < N) ? cnt[i0 + 1] : 0;
    int v2 = (i0 + 2 < N) ? cnt[i0 + 2] : 0;
    int v3 = (i0 + 3 < N) ? cnt[i0 + 3] : 0;
    sh[t] = v0 + v1 + v2 + v3;
    __syncthreads();
    for (int o = 1; o < 256; o <<= 1) {
        int y = (t >= o) ? sh[t - o] : 0;
        __syncthreads();
        sh[t] += y;
        __syncthreads();
    }
    int off = bsum[blockIdx.x] + ((t > 0) ? sh[t - 1] : 0);
    if (i0 + 0 < N) row_ptr[i0 + 0] = off;  off += v0;
    if (i0 + 1 < N) row_ptr[i0 + 1] = off;  off += v1;
    if (i0 + 2 < N) row_ptr[i0 + 2] = off;  off += v2;
    if (i0 + 3 < N) row_ptr[i0 + 3] = off;
    if (blockIdx.x == 0 && t == 0) row_ptr[N] = E;
}

__global__ void fill_sorted4_kernel(const int* __restrict__ src, const int* __restrict__ dst,
                                    const int* __restrict__ row_ptr, int* __restrict__ cursor,
                                    int* __restrict__ sorted_src, int E) {
    int i = blockIdx.x * blockDim.x + threadIdx.x;
    int base = i * 4;
    if (base + 3 < E) {
        int4 d = *reinterpret_cast<const int4*>(dst + base);
        int4 s = *reinterpret_cast<const int4*>(src + base);
        int r0 = row_ptr[d.x];
        int r1 = row_ptr[d.y];
        int r2 = row_ptr[d.z];
        int r3 = row_ptr[d.w];
        int k0 = atomicAdd(&cursor[d.x], 1);
        int k1 = atomicAdd(&cursor[d.y], 1);
        int k2 = atomicAdd(&cursor[d.z], 1);
        int k3 = atomicAdd(&cursor[d.w], 1);
        sorted_src[r0 + k0] = s.x;
        sorted_src[r1 + k1] = s.y;
        sorted_src[r2 + k2] = s.z;
        sorted_src[r3 + k3] = s.w;
    } else {
        for (int e = base; e < E; ++e) {
            int dd = dst[e];
            int pos = row_ptr[dd] + atomicAdd(&cursor[dd], 1);
            sorted_src[pos] = src[e];
        }
    }
}

// ===================== degree-binned node permutation (contention-free) =====================
// Counting sort by degree: per-block LDS hist -> column scan -> LDS-cursor scatter.
// Waves then process equal-degree nodes -> serial gather depth = own degree.

#define DBINS 64
#define DB_BLK 256

// A: per-block histogram into H[block][DBINS]
__global__ void degbin_blockhist_kernel(const int* __restrict__ row_ptr, int* __restrict__ H, int N) {
    __shared__ int lh[DBINS];
    int t = threadIdx.x;
    if (t < DBINS) lh[t] = 0;
    __syncthreads();
    int n = blockIdx.x * DB_BLK + t;
    if (n < N) {
        int d = row_ptr[n + 1] - row_ptr[n];
        int b = (d < DBINS) ? d : (DBINS - 1);
        atomicAdd(&lh[b], 1);  // LDS atomic
    }
    __syncthreads();
    if (t < DBINS) H[(long long)blockIdx.x * DBINS + t] = lh[t];
}

// B: single block, 1024 threads = 16 chunks x 64 bins; exclusive scan of each bin column,
// then add bin base -> H[block][bin] = global start offset for that (block,bin)
__global__ void degbin_colscan_kernel(int* __restrict__ H, int nb) {
    __shared__ int C[16 * DBINS];
    __shared__ int tot[DBINS];
    __shared__ int base[DBINS];
    int t = threadIdx.x;
    int chunk = t >> 6;
    int b = t & 63;
    int per = (nb + 15) / 16;
    int k0 = chunk * per;
    int k1 = (k0 + per < nb) ? k0 + per : nb;
    int acc = 0;
    for (int k = k0; k < k1; ++k) {
        int v = H[(long long)k * DBINS + b];
        H[(long long)k * DBINS + b] = acc;
        acc += v;
    }
    C[chunk * DBINS + b] = acc;
    __syncthreads();
    if (chunk == 0) {
        int a = 0;
#pragma unroll
        for (int c = 0; c < 16; ++c) { int v = C[c * DBINS + b]; C[c * DBINS + b] = a; a += v; }
        tot[b] = a;
    }
    __syncthreads();
    if (t == 0) {
        int a = 0;
        for (int i = 0; i < DBINS; ++i) { base[i] = a; a += tot[i]; }
    }
    __syncthreads();
    int add = base[b] + C[chunk * DBINS + b];
    for (int k = k0; k < k1; ++k) H[(long long)k * DBINS + b] += add;
}

// C: scatter with per-block LDS cursors (no global atomics)
__global__ void degbin_scatter_kernel(const int* __restrict__ row_ptr, const int* __restrict__ H,
                                      int* __restrict__ perm, int N) {
    __shared__ int cur[DBINS];
    int t = threadIdx.x;
    if (t < DBINS) cur[t] = H[(long long)blockIdx.x * DBINS + t];
    __syncthreads();
    int n = blockIdx.x * DB_BLK + t;
    if (n < N) {
        int d = row_ptr[n + 1] - row_ptr[n];
        int b = (d < DBINS) ? d : (DBINS - 1);
        int pos = atomicAdd(&cur[b], 1);  // LDS atomic
        perm[pos] = n;
    }
}

// ===================== fp16 row helpers (packed half2) =====================

template <int SH>
__device__ __forceinline__ void load_row_h2(__half2* __restrict__ acc, const __half* __restrict__ row) {
#pragma unroll
    for (int u = 0; u < SH / 8; ++u) {
        union { float4 f4; __half2 h2[4]; } ld;
        ld.f4 = *reinterpret_cast<const float4*>(row + u * 8);
#pragma unroll
        for (int k = 0; k < 4; ++k) acc[u * 4 + k] = ld.h2[k];
    }
}

template <int SH>
__device__ __forceinline__ void fmax_row_h2(__half2* __restrict__ acc, const __half* __restrict__ row) {
#pragma unroll
    for (int u = 0; u < SH / 8; ++u) {
        union { float4 f4; __half2 h2[4]; } ld;
        ld.f4 = *reinterpret_cast<const float4*>(row + u * 8);
#pragma unroll
        for (int k = 0; k < 4; ++k) acc[u * 4 + k] = hmax2(acc[u * 4 + k], ld.h2[k]);
    }
}

template <int FOUT, int SOUTH>
__device__ __forceinline__ void store_row_h(__half* __restrict__ op,
                                            const float* __restrict__ vals, float dv) {
#pragma unroll
    for (int u = 0; u < SOUTH / 8; ++u) {
        union { float4 f4; __half2 h2[4]; } pk;
#pragma unroll
        for (int k = 0; k < 4; ++k) {
            int f0 = u * 8 + 2 * k, f1 = f0 + 1;
            float a = (f0 < FOUT) ? vals[(f0 < FOUT) ? f0 : 0] * dv : 0.0f;
            float b = (f1 < FOUT) ? vals[(f1 < FOUT) ? f1 : 0] * dv : 0.0f;
            pk.h2[k] = __floats2half2_rn(a, b);
        }
        *reinterpret_cast<float4*>(op + u * 8) = pk.f4;
    }
}

// neighbor max loop, unroll-4 (4 independent row loads in flight)
template <int SH>
__device__ __forceinline__ void gather_max_loop(__half2* __restrict__ acc,
                                                const __half* __restrict__ u,
                                                const int* __restrict__ sorted_src,
                                                int j0, int j1) {
    int j = j0;
    for (; j + 4 <= j1; j += 4) {
        int s0 = sorted_src[j + 0];
        int s1 = sorted_src[j + 1];
        int s2 = sorted_src[j + 2];
        int s3 = sorted_src[j + 3];
        fmax_row_h2<SH>(acc, u + (long long)s0 * SH);
        fmax_row_h2<SH>(acc, u + (long long)s1 * SH);
        fmax_row_h2<SH>(acc, u + (long long)s2 * SH);
        fmax_row_h2<SH>(acc, u + (long long)s3 * SH);
    }
    for (; j < j1; ++j) fmax_row_h2<SH>(acc, u + (long long)sorted_src[j] * SH);
}

// ===================== layer kernels =====================

// layer-1 GEMM: u1[n,:] = half((x[n,:] @ W1) * dinv[n])
template <int FIN, int FOUT, int SOUTH>
__global__ void gemm_scale_kernel(const float* __restrict__ h,
                                  const float* __restrict__ W,
                                  const float* __restrict__ dinv,
                                  __half* __restrict__ u,
                                  int N) {
    int n = blockIdx.x * blockDim.x + threadIdx.x;
    if (n >= N) return;
    const float* hr = h + (long long)n * FIN;
    float acc[FOUT];
#pragma unroll
    for (int c = 0; c < FOUT; ++c) acc[c] = 0.0f;
#pragma unroll
    for (int fi = 0; fi < FIN; ++fi) {
        float hv = hr[fi];
#pragma unroll
        for (int c = 0; c < FOUT; ++c) acc[c] += hv * W[fi * FOUT + c];
    }
    store_row_h<FOUT, SOUTH>(u + (long long)n * SOUTH, acc, dinv[n]);
}

// fused agg + next-layer GEMM, thread per node (degree-permuted)
template <int SPREVH, int FPREV, int FOUT, int SOUTH>
__global__ void agg_gemm_kernel(const __half* __restrict__ u,
                                const int* __restrict__ row_ptr,
                                const int* __restrict__ sorted_src,
                                const int* __restrict__ perm,
                                const float* __restrict__ dinv,
                                const float* __restrict__ bprev,
                                const float* __restrict__ W,
                                __half* __restrict__ uout,
                                int N) {
    int gid = blockIdx.x * blockDim.x + threadIdx.x;
    if (gid >= N) return;
    int n = perm[gid];
    __half2 acc[SPREVH / 2];
    load_row_h2<SPREVH>(acc, u + (long long)n * SPREVH);  // self loop
    int j0 = row_ptr[n], j1 = row_ptr[n + 1];
    gather_max_loop<SPREVH>(acc, u, sorted_src, j0, j1);

    float af[SPREVH];
#pragma unroll
    for (int i = 0; i < SPREVH / 2; ++i) {
        float2 p = __half22float2(acc[i]);
        af[2 * i] = p.x;
        af[2 * i + 1] = p.y;
    }
    float dv = dinv[n];
    float h[FPREV];
#pragma unroll
    for (int f = 0; f < FPREV; ++f) {
        float v = dv * af[f] + bprev[f];
        h[f] = (v > 0.0f) ? (SELU_SCALE * v) : (SELU_SCALE * SELU_ALPHA * (expf(v) - 1.0f));
    }
    float outv[FOUT];
#pragma unroll
    for (int c = 0; c < FOUT; ++c) outv[c] = 0.0f;
#pragma unroll
    for (int fi = 0; fi < FPREV; ++fi) {
        float hv = h[fi];
#pragma unroll
        for (int c = 0; c < FOUT; ++c) outv[c] += hv * W[fi * FOUT + c];
    }
    store_row_h<FOUT, SOUTH>(uout + (long long)n * SOUTH, outv, dv);
}

// final aggregation (layer 4): fp32 output stride F, thread per node (permuted)
template <int SH, int F>
__global__ void agg_selu_kernel(const __half* __restrict__ u,
                                const int* __restrict__ row_ptr,
                                const int* __restrict__ sorted_src,
                                const int* __restrict__ perm,
                                const float* __restrict__ dinv,
                                const float* __restrict__ b,
                                float* __restrict__ hout,
                                int N) {
    int gid = blockIdx.x * blockDim.x + threadIdx.x;
    if (gid >= N) return;
    int n = perm[gid];
    __half2 acc[SH / 2];
    load_row_h2<SH>(acc, u + (long long)n * SH);
    int j0 = row_ptr[n], j1 = row_ptr[n + 1];
    gather_max_loop<SH>(acc, u, sorted_src, j0, j1);

    float dv = dinv[n];
    float* op = hout + (long long)n * F;
#pragma unroll
    for (int q = 0; q < F / 4; ++q) {
        float4 o;
        float* ov = &o.x;
#pragma unroll
        for (int k = 0; k < 4; ++k) {
            int f = 4 * q + k;
            float2 p = __half22float2(acc[f / 2]);
            float raw = (f & 1) ? p.y : p.x;
            float v = dv * raw + b[f];
            ov[k] = (v > 0.0f) ? (SELU_SCALE * v) : (SELU_SCALE * SELU_ALPHA * (expf(v) - 1.0f));
        }
        *reinterpret_cast<float4*>(op + 4 * q) = o;
    }
}

// ===================== pooling =====================

__global__ void segstart_kernel(const int* __restrict__ batch, int* __restrict__ seg, int N, int G) {
    int g = blockIdx.x * blockDim.x + threadIdx.x;
    if (g > G) return;
    if (g == G) { seg[G] = N; return; }
    int lo = 0, hi = N;
    while (lo < hi) { int mid = (lo + hi) >> 1; if (batch[mid] < g) lo = mid + 1; else hi = mid; }
    seg[g] = lo;
}

__global__ void pool_kernel(const float* __restrict__ h,
                            const int* __restrict__ seg,
                            float* __restrict__ pooled,
                            int G) {
    int idx = blockIdx.x * blockDim.x + threadIdx.x;  // G * 9
    if (idx >= G * 9) return;
    int g = idx / 9;
    int t = idx - g * 9;
    int lo = seg[g], hi = seg[g + 1];
    float4 acc = make_float4(0.f, 0.f, 0.f, 0.f);
    for (int n = lo; n < hi; ++n) {
        float4 v = *reinterpret_cast<const float4*>(h + (long long)n * 36 + 4 * t);
        acc.x += v.x; acc.y += v.y; acc.z += v.z; acc.w += v.w;
    }
    *reinterpret_cast<float4*>(pooled + (long long)g * 36 + 4 * t) = acc;
}

// ===================== MLP head =====================

__global__ void mlp1_kernel(const float* __restrict__ pooled,
                            const float* __restrict__ lw1,
                            const float* __restrict__ lb1,
                            float* __restrict__ y1,
                            int G) {
    __shared__ float Ws[36 * 96];
    for (int i = threadIdx.x; i < 36 * 96; i += blockDim.x) Ws[i] = lw1[i];
    __syncthreads();
    int idx = blockIdx.x * blockDim.x + threadIdx.x;
    if (idx >= G * 96) return;
    int g = idx / 96;
    int j = idx - g * 96;
    const float* pr = pooled + (long long)g * 36;
    float acc = lb1[j];
#pragma unroll
    for (int k4 = 0; k4 < 9; ++k4) {
        float4 pv = *reinterpret_cast<const float4*>(pr + 4 * k4);
        acc += pv.x * Ws[(4 * k4 + 0) * 96 + j];
        acc += pv.y * Ws[(4 * k4 + 1) * 96 + j];
        acc += pv.z * Ws[(4 * k4 + 2) * 96 + j];
        acc += pv.w * Ws[(4 * k4 + 3) * 96 + j];
    }
    y1[idx] = fmaxf(acc, 0.0f);
}

__global__ void mlp2_kernel(const float* __restrict__ y1,
                            const float* __restrict__ lw2,
                            const float* __restrict__ lb2,
                            float* __restrict__ out,
                            int G) {
    __shared__ float Ws[96 * 27];
    for (int i = threadIdx.x; i < 96 * 27; i += blockDim.x) Ws[i] = lw2[i];
    __syncthreads();
    int idx = blockIdx.x * blockDim.x + threadIdx.x;
    if (idx >= G * 27) return;
    int g = idx / 27;
    int c = idx - g * 27;
    const float* yr = y1 + (long long)g * 96;
    float acc = lb2[c];
#pragma unroll
    for (int k4 = 0; k4 < 24; ++k4) {
        float4 yv = *reinterpret_cast<const float4*>(yr + 4 * k4);
        acc += yv.x * Ws[(4 * k4 + 0) * 27 + c];
        acc += yv.y * Ws[(4 * k4 + 1) * 27 + c];
        acc += yv.z * Ws[(4 * k4 + 2) * 27 + c];
        acc += yv.w * Ws[(4 * k4 + 3) * 27 + c];
    }
    out[idx] = fmaxf(acc, 0.0f);
}

// ===================== launch =====================

extern "C" void kernel_launch(void* const* d_in, const int* in_sizes, int n_in,
                              void* d_out, int out_size, void* d_ws, size_t ws_size,
                              hipStream_t stream) {
    const float* x     = (const float*)d_in[0];
    const int*   ei    = (const int*)d_in[1];
    const int*   batch = (const int*)d_in[2];
    const float* W1  = (const float*)d_in[4];
    const float* b1  = (const float*)d_in[5];
    const float* W2  = (const float*)d_in[6];
    const float* b2  = (const float*)d_in[7];
    const float* W3  = (const float*)d_in[8];
    const float* b3  = (const float*)d_in[9];
    const float* W4  = (const float*)d_in[10];
    const float* b4  = (const float*)d_in[11];
    const float* lw1 = (const float*)d_in[12];
    const float* lb1 = (const float*)d_in[13];
    const float* lw2 = (const float*)d_in[14];
    const float* lb2 = (const float*)d_in[15];
    float* out = (float*)d_out;

    const int N = in_sizes[0] / 75;
    const int E = in_sizes[1] / 2;
    const int G = out_size / 27;
    const int* srcp = ei;
    const int* dstp = ei + E;

    char* ws = (char*)d_ws;
    size_t off = 0;
    auto carve = [&](size_t bytes) -> char* {
        char* p = ws + off;
        off = (off + bytes + 255) & ~(size_t)255;
        return p;
    };
    const int nbH = cdiv(N, DB_BLK);
    int*    cnt        = (int*)carve((size_t)N * 4);
    int*    row_ptr    = (int*)carve((size_t)(N + 1) * 4);
    int*    sorted_src = (int*)carve((size_t)E * 4);
    int*    bsum       = (int*)carve((size_t)cdiv(N, 1024) * 4 + 4);
    int*    seg        = (int*)carve((size_t)(G + 1) * 4);
    int*    perm       = (int*)carve((size_t)N * 4);
    int*    H          = (int*)carve((size_t)nbH * DBINS * 4);
    float*  dinv       = (float*)carve((size_t)N * 4);
    char*   Abuf       = carve((size_t)N * 36 * 4);
    char*   Bbuf       = carve((size_t)N * 36 * 4);
    float*  pooled     = (float*)carve((size_t)G * 36 * 4);
    float*  y1         = (float*)carve((size_t)G * 96 * 4);
    (void)ws_size; (void)n_in;

    const int BLK = 256;
    const int nb = cdiv(N, 1024);

    // ---- edge preprocessing ----
    zero_int_kernel<<<cdiv(N, BLK), BLK, 0, stream>>>(cnt, N);
    hist4_kernel<<<cdiv(cdiv(E, 4), BLK), BLK, 0, stream>>>(dstp, cnt, E);
    dinv_kernel<<<cdiv(N, BLK), BLK, 0, stream>>>(cnt, dinv, N);
    scan_partial_kernel<<<nb, 256, 0, stream>>>(cnt, bsum, N);
    if (nb <= 1024) scan_bsum_par_kernel<<<1, 1024, 0, stream>>>(bsum, nb);
    else            scan_bsum_serial_kernel<<<1, 64, 0, stream>>>(bsum, nb);
    scan_final_kernel<<<nb, 256, 0, stream>>>(cnt, bsum, row_ptr, N, E);
    zero_int_kernel<<<cdiv(N, BLK), BLK, 0, stream>>>(cnt, N);  // cursor = 0
    fill_sorted4_kernel<<<cdiv(cdiv(E, 4), BLK), BLK, 0, stream>>>(srcp, dstp, row_ptr, cnt, sorted_src, E);
    segstart_kernel<<<cdiv(G + 1, BLK), BLK, 0, stream>>>(batch, seg, N, G);

    // ---- degree-binned permutation (contention-free counting sort) ----
    degbin_blockhist_kernel<<<nbH, DB_BLK, 0, stream>>>(row_ptr, H, N);
    degbin_colscan_kernel<<<1, 1024, 0, stream>>>(H, nbH);
    degbin_scatter_kernel<<<nbH, DB_BLK, 0, stream>>>(row_ptr, H, perm, N);

    // fp16 u strides (halves): u1=16 (32B), u2=32 (64B line), u3=32 (64B line), u4=40 (80B)
    __half* u1 = (__half*)Bbuf;
    __half* u2 = (__half*)Abuf;
    __half* u3 = (__half*)Bbuf;
    __half* u4 = (__half*)Abuf;
    float*  h4 = (float*)Bbuf;

    gemm_scale_kernel<75, 15, 16><<<cdiv(N, BLK), BLK, 0, stream>>>(x, W1, dinv, u1, N);
    agg_gemm_kernel<16, 15, 20, 32><<<cdiv(N, BLK), BLK, 0, stream>>>(u1, row_ptr, sorted_src, perm, dinv, b1, W2, u2, N);
    agg_gemm_kernel<32, 20, 27, 32><<<cdiv(N, BLK), BLK, 0, stream>>>(u2, row_ptr, sorted_src, perm, dinv, b2, W3, u3, N);
    agg_gemm_kernel<32, 27, 36, 40><<<cdiv(N, BLK), BLK, 0, stream>>>(u3, row_ptr, sorted_src, perm, dinv, b3, W4, u4, N);
    agg_selu_kernel<40, 36><<<cdiv(N, BLK), BLK, 0, stream>>>(u4, row_ptr, sorted_src, perm, dinv, b4, h4, N);

    // ---- pool: segmented sum (batch_vec is sorted) ----
    pool_kernel<<<cdiv((long long)G * 9, BLK), BLK, 0, stream>>>(h4, seg, pooled, G);

    // ---- MLP head ----
    mlp1_kernel<<<cdiv((long long)G * 96, BLK), BLK, 0, stream>>>(pooled, lw1, lb1, y1, G);
    mlp2_kernel<<<cdiv((long long)G * 27, BLK), BLK, 0, stream>>>(y1, lw2, lb2, out, G);
}

// Round 11
// 1192.231 us; speedup vs baseline: 7.8850x; 1.1262x over previous
//
#include <hip/hip_runtime.h>
#include <hip/hip_fp16.h>
#include <math.h>

#define SELU_SCALE 1.0507009873554805f
#define SELU_ALPHA 1.6732632423543772f

static inline int cdiv(long long a, int b) { return (int)((a + b - 1) / b); }

// packed fp16 max (v_pk_max_f16) — __hmax2 intrinsic is missing on this ROCm
__device__ __forceinline__ __half2 hmax2(__half2 a, __half2 b) {
    __half2 r;
    asm("v_pk_max_f16 %0, %1, %2" : "=v"(r) : "v"(a), "v"(b));
    return r;
}

// ===================== generic small kernels =====================

__global__ void zero_int_kernel(int* __restrict__ p, int n) {
    int i = blockIdx.x * blockDim.x + threadIdx.x;
    if (i < n) p[i] = 0;
}

__global__ void dinv_kernel(const int* __restrict__ cnt, float* __restrict__ dinv, int N) {
    int i = blockIdx.x * blockDim.x + threadIdx.x;
    if (i < N) dinv[i] = rsqrtf((float)cnt[i] + 1.0f);  // +1 self loop
}

// ===================== edge bucketing (256 coarse buckets by dst>>shift) =====================
// Purpose: localize all later per-dst atomics/reads/writes to ~64KB regions
// (kills the 16x write amplification of fully-random CSR fill).

#define NBUK 256
#define BUK_EDGES 4096  // edges per block (256 threads x 16)

__global__ void buk_count_kernel(const int* __restrict__ dst, int* __restrict__ HB,
                                 int E, int shift) {
    __shared__ int lh[NBUK];
    int t = threadIdx.x;
    lh[t] = 0;
    __syncthreads();
    int e0 = blockIdx.x * BUK_EDGES + t * 16;
#pragma unroll
    for (int k = 0; k < 16; k += 4) {
        int e = e0 + k;
        if (e + 3 < E) {
            int4 d = *reinterpret_cast<const int4*>(dst + e);
            atomicAdd(&lh[d.x >> shift], 1);
            atomicAdd(&lh[d.y >> shift], 1);
            atomicAdd(&lh[d.z >> shift], 1);
            atomicAdd(&lh[d.w >> shift], 1);
        } else {
            for (int q = e; q < E && q < e + 4; ++q) atomicAdd(&lh[dst[q] >> shift], 1);
        }
    }
    __syncthreads();
    HB[blockIdx.x * NBUK + t] = lh[t];
}

// single block, 1024 threads = 4 chunks x 256 buckets; exclusive column scan + bucket base
__global__ void buk_colscan_kernel(int* __restrict__ HB, int nblk) {
    __shared__ int C[4 * NBUK];
    __shared__ int tot[NBUK];
    __shared__ int base[NBUK];
    int t = threadIdx.x;
    int chunk = t >> 8;
    int b = t & 255;
    int per = (nblk + 3) / 4;
    int k0 = chunk * per;
    int k1 = (k0 + per < nblk) ? k0 + per : nblk;
    int acc = 0;
    for (int k = k0; k < k1; ++k) {
        int v = HB[(long long)k * NBUK + b];
        HB[(long long)k * NBUK + b] = acc;
        acc += v;
    }
    C[chunk * NBUK + b] = acc;
    __syncthreads();
    if (chunk == 0) {
        int a = 0;
#pragma unroll
        for (int c = 0; c < 4; ++c) { int v = C[c * NBUK + b]; C[c * NBUK + b] = a; a += v; }
        tot[b] = a;
    }
    __syncthreads();
    if (t == 0) {
        int a = 0;
        for (int i = 0; i < NBUK; ++i) { base[i] = a; a += tot[i]; }
    }
    __syncthreads();
    int add = base[b] + C[chunk * NBUK + b];
    for (int k = k0; k < k1; ++k) HB[(long long)k * NBUK + b] += add;
}

__global__ void buk_scatter_kernel(const int* __restrict__ src, const int* __restrict__ dst,
                                   const int* __restrict__ HB, int2* __restrict__ ebuf,
                                   int E, int shift) {
    __shared__ int cur[NBUK];
    int t = threadIdx.x;
    cur[t] = HB[blockIdx.x * NBUK + t];
    __syncthreads();
    int e0 = blockIdx.x * BUK_EDGES + t * 16;
#pragma unroll
    for (int k = 0; k < 16; k += 4) {
        int e = e0 + k;
        if (e + 3 < E) {
            int4 d = *reinterpret_cast<const int4*>(dst + e);
            int4 s = *reinterpret_cast<const int4*>(src + e);
            int p0 = atomicAdd(&cur[d.x >> shift], 1);
            int p1 = atomicAdd(&cur[d.y >> shift], 1);
            int p2 = atomicAdd(&cur[d.z >> shift], 1);
            int p3 = atomicAdd(&cur[d.w >> shift], 1);
            ebuf[p0] = make_int2(s.x, d.x);
            ebuf[p1] = make_int2(s.y, d.y);
            ebuf[p2] = make_int2(s.z, d.z);
            ebuf[p3] = make_int2(s.w, d.w);
        } else {
            for (int q = e; q < E && q < e + 4; ++q) {
                int dd = dst[q];
                int p = atomicAdd(&cur[dd >> shift], 1);
                ebuf[p] = make_int2(src[q], dd);
            }
        }
    }
}

// histogram from bucketed edges: atomics hit ~16KB-hot cnt regions
__global__ void hist_ebuf_kernel(const int2* __restrict__ ebuf, int* __restrict__ cnt, int E) {
    int i = blockIdx.x * blockDim.x + threadIdx.x;
    int e0 = i * 4;
    if (e0 + 3 < E) {
        int4 a = *reinterpret_cast<const int4*>(ebuf + e0);      // (s0,d0,s1,d1)
        int4 b = *reinterpret_cast<const int4*>(ebuf + e0 + 2);  // (s2,d2,s3,d3)
        atomicAdd(&cnt[a.y], 1);
        atomicAdd(&cnt[a.w], 1);
        atomicAdd(&cnt[b.y], 1);
        atomicAdd(&cnt[b.w], 1);
    } else {
        for (int e = e0; e < E; ++e) atomicAdd(&cnt[ebuf[e].y], 1);
    }
}

// CSR fill from bucketed edges: row_ptr reads / cursor atomics / sorted_src writes all localized
__global__ void fill_ebuf_kernel(const int2* __restrict__ ebuf, const int* __restrict__ row_ptr,
                                 int* __restrict__ cursor, int* __restrict__ sorted_src, int E) {
    int i = blockIdx.x * blockDim.x + threadIdx.x;
    int e0 = i * 4;
    if (e0 + 3 < E) {
        int4 a = *reinterpret_cast<const int4*>(ebuf + e0);
        int4 b = *reinterpret_cast<const int4*>(ebuf + e0 + 2);
        int r0 = row_ptr[a.y];
        int r1 = row_ptr[a.w];
        int r2 = row_ptr[b.y];
        int r3 = row_ptr[b.w];
        int k0 = atomicAdd(&cursor[a.y], 1);
        int k1 = atomicAdd(&cursor[a.w], 1);
        int k2 = atomicAdd(&cursor[b.y], 1);
        int k3 = atomicAdd(&cursor[b.w], 1);
        sorted_src[r0 + k0] = a.x;
        sorted_src[r1 + k1] = a.z;
        sorted_src[r2 + k2] = b.x;
        sorted_src[r3 + k3] = b.z;
    } else {
        for (int e = e0; e < E; ++e) {
            int2 ed = ebuf[e];
            int pos = row_ptr[ed.y] + atomicAdd(&cursor[ed.y], 1);
            sorted_src[pos] = ed.x;
        }
    }
}

// ===================== scans for row_ptr =====================

__global__ void scan_partial_kernel(const int* __restrict__ cnt, int* __restrict__ bsum, int N) {
    __shared__ int sh[256];
    int base = blockIdx.x * 1024;
    int t = threadIdx.x;
    int s = 0;
#pragma unroll
    for (int k = 0; k < 4; ++k) {
        int i = base + t * 4 + k;
        if (i < N) s += cnt[i];
    }
    sh[t] = s;
    __syncthreads();
    for (int o = 128; o > 0; o >>= 1) {
        if (t < o) sh[t] += sh[t + o];
        __syncthreads();
    }
    if (t == 0) bsum[blockIdx.x] = sh[0];
}

__global__ void scan_bsum_par_kernel(int* __restrict__ bsum, int nb) {
    __shared__ int sh[1024];
    int t = threadIdx.x;
    int v = (t < nb) ? bsum[t] : 0;
    sh[t] = v;
    __syncthreads();
    for (int o = 1; o < 1024; o <<= 1) {
        int y = (t >= o) ? sh[t - o] : 0;
        __syncthreads();
        sh[t] += y;
        __syncthreads();
    }
    if (t < nb) bsum[t] = sh[t] - v;
}

__global__ void scan_bsum_serial_kernel(int* __restrict__ bsum, int nb) {
    if (blockIdx.x == 0 && threadIdx.x == 0) {
        int acc = 0;
        for (int i = 0; i < nb; ++i) { int v = bsum[i]; bsum[i] = acc; acc += v; }
    }
}

__global__ void scan_final_kernel(const int* __restrict__ cnt, const int* __restrict__ bsum,
                                  int* __restrict__ row_ptr, int N, int E) {
    __shared__ int sh[256];
    int base = blockIdx.x * 1024;
    int t = threadIdx.x;
    int i0 = base + t * 4;
    int v0 = (i0 + 0 < N) ? cnt[i0 + 0] : 0;
    int v1 = (i0 + 1 < N) ? cnt[i0 + 1] : 0;
    int v2 = (i0 + 2 < N) ? cnt[i0 + 2] : 0;
    int v3 = (i0 + 3 < N) ? cnt[i0 + 3] : 0;
    sh[t] = v0 + v1 + v2 + v3;
    __syncthreads();
    for (int o = 1; o < 256; o <<= 1) {
        int y = (t >= o) ? sh[t - o] : 0;
        __syncthreads();
        sh[t] += y;
        __syncthreads();
    }
    int off = bsum[blockIdx.x] + ((t > 0) ? sh[t - 1] : 0);
    if (i0 + 0 < N) row_ptr[i0 + 0] = off;  off += v0;
    if (i0 + 1 < N) row_ptr[i0 + 1] = off;  off += v1;
    if (i0 + 2 < N) row_ptr[i0 + 2] = off;  off += v2;
    if (i0 + 3 < N) row_ptr[i0 + 3] = off;
    if (blockIdx.x == 0 && t == 0) row_ptr[N] = E;
}

// ===================== fp16 row helpers (packed half2) =====================

template <int SH>
__device__ __forceinline__ void load_row_h2(__half2* __restrict__ acc, const __half* __restrict__ row) {
#pragma unroll
    for (int u = 0; u < SH / 8; ++u) {
        union { float4 f4; __half2 h2[4]; } ld;
        ld.f4 = *reinterpret_cast<const float4*>(row + u * 8);
#pragma unroll
        for (int k = 0; k < 4; ++k) acc[u * 4 + k] = ld.h2[k];
    }
}

template <int SH>
__device__ __forceinline__ void fmax_row_h2(__half2* __restrict__ acc, const __half* __restrict__ row) {
#pragma unroll
    for (int u = 0; u < SH / 8; ++u) {
        union { float4 f4; __half2 h2[4]; } ld;
        ld.f4 = *reinterpret_cast<const float4*>(row + u * 8);
#pragma unroll
        for (int k = 0; k < 4; ++k) acc[u * 4 + k] = hmax2(acc[u * 4 + k], ld.h2[k]);
    }
}

template <int FOUT, int SOUTH>
__device__ __forceinline__ void store_row_h(__half* __restrict__ op,
                                            const float* __restrict__ vals, float dv) {
#pragma unroll
    for (int u = 0; u < SOUTH / 8; ++u) {
        union { float4 f4; __half2 h2[4]; } pk;
#pragma unroll
        for (int k = 0; k < 4; ++k) {
            int f0 = u * 8 + 2 * k, f1 = f0 + 1;
            float a = (f0 < FOUT) ? vals[(f0 < FOUT) ? f0 : 0] * dv : 0.0f;
            float b = (f1 < FOUT) ? vals[(f1 < FOUT) ? f1 : 0] * dv : 0.0f;
            pk.h2[k] = __floats2half2_rn(a, b);
        }
        *reinterpret_cast<float4*>(op + u * 8) = pk.f4;
    }
}

// neighbor max loop, unroll-4 (4 independent row loads in flight)
template <int SH>
__device__ __forceinline__ void gather_max_loop(__half2* __restrict__ acc,
                                                const __half* __restrict__ u,
                                                const int* __restrict__ sorted_src,
                                                int j0, int j1) {
    int j = j0;
    for (; j + 4 <= j1; j += 4) {
        int s0 = sorted_src[j + 0];
        int s1 = sorted_src[j + 1];
        int s2 = sorted_src[j + 2];
        int s3 = sorted_src[j + 3];
        fmax_row_h2<SH>(acc, u + (long long)s0 * SH);
        fmax_row_h2<SH>(acc, u + (long long)s1 * SH);
        fmax_row_h2<SH>(acc, u + (long long)s2 * SH);
        fmax_row_h2<SH>(acc, u + (long long)s3 * SH);
    }
    for (; j < j1; ++j) fmax_row_h2<SH>(acc, u + (long long)sorted_src[j] * SH);
}

// ===================== layer kernels =====================

// layer-1 GEMM: u1[n,:] = half((x[n,:] @ W1) * dinv[n])
template <int FIN, int FOUT, int SOUTH>
__global__ void gemm_scale_kernel(const float* __restrict__ h,
                                  const float* __restrict__ W,
                                  const float* __restrict__ dinv,
                                  __half* __restrict__ u,
                                  int N) {
    int n = blockIdx.x * blockDim.x + threadIdx.x;
    if (n >= N) return;
    const float* hr = h + (long long)n * FIN;
    float acc[FOUT];
#pragma unroll
    for (int c = 0; c < FOUT; ++c) acc[c] = 0.0f;
#pragma unroll
    for (int fi = 0; fi < FIN; ++fi) {
        float hv = hr[fi];
#pragma unroll
        for (int c = 0; c < FOUT; ++c) acc[c] += hv * W[fi * FOUT + c];
    }
    store_row_h<FOUT, SOUTH>(u + (long long)n * SOUTH, acc, dinv[n]);
}

// fused agg + next-layer GEMM, thread per node (identity order: coalesced self/store)
template <int SPREVH, int FPREV, int FOUT, int SOUTH>
__global__ void agg_gemm_kernel(const __half* __restrict__ u,
                                const int* __restrict__ row_ptr,
                                const int* __restrict__ sorted_src,
                                const float* __restrict__ dinv,
                                const float* __restrict__ bprev,
                                const float* __restrict__ W,
                                __half* __restrict__ uout,
                                int N) {
    int n = blockIdx.x * blockDim.x + threadIdx.x;
    if (n >= N) return;
    __half2 acc[SPREVH / 2];
    load_row_h2<SPREVH>(acc, u + (long long)n * SPREVH);  // self loop
    int j0 = row_ptr[n], j1 = row_ptr[n + 1];
    gather_max_loop<SPREVH>(acc, u, sorted_src, j0, j1);

    float af[SPREVH];
#pragma unroll
    for (int i = 0; i < SPREVH / 2; ++i) {
        float2 p = __half22float2(acc[i]);
        af[2 * i] = p.x;
        af[2 * i + 1] = p.y;
    }
    float dv = dinv[n];
    float h[FPREV];
#pragma unroll
    for (int f = 0; f < FPREV; ++f) {
        float v = dv * af[f] + bprev[f];
        h[f] = (v > 0.0f) ? (SELU_SCALE * v) : (SELU_SCALE * SELU_ALPHA * (expf(v) - 1.0f));
    }
    float outv[FOUT];
#pragma unroll
    for (int c = 0; c < FOUT; ++c) outv[c] = 0.0f;
#pragma unroll
    for (int fi = 0; fi < FPREV; ++fi) {
        float hv = h[fi];
#pragma unroll
        for (int c = 0; c < FOUT; ++c) outv[c] += hv * W[fi * FOUT + c];
    }
    store_row_h<FOUT, SOUTH>(uout + (long long)n * SOUTH, outv, dv);
}

// final aggregation (layer 4): fp32 output stride F
template <int SH, int F>
__global__ void agg_selu_kernel(const __half* __restrict__ u,
                                const int* __restrict__ row_ptr,
                                const int* __restrict__ sorted_src,
                                const float* __restrict__ dinv,
                                const float* __restrict__ b,
                                float* __restrict__ hout,
                                int N) {
    int n = blockIdx.x * blockDim.x + threadIdx.x;
    if (n >= N) return;
    __half2 acc[SH / 2];
    load_row_h2<SH>(acc, u + (long long)n * SH);
    int j0 = row_ptr[n], j1 = row_ptr[n + 1];
    gather_max_loop<SH>(acc, u, sorted_src, j0, j1);

    float dv = dinv[n];
    float* op = hout + (long long)n * F;
#pragma unroll
    for (int q = 0; q < F / 4; ++q) {
        float4 o;
        float* ov = &o.x;
#pragma unroll
        for (int k = 0; k < 4; ++k) {
            int f = 4 * q + k;
            float2 p = __half22float2(acc[f / 2]);
            float raw = (f & 1) ? p.y : p.x;
            float v = dv * raw + b[f];
            ov[k] = (v > 0.0f) ? (SELU_SCALE * v) : (SELU_SCALE * SELU_ALPHA * (expf(v) - 1.0f));
        }
        *reinterpret_cast<float4*>(op + 4 * q) = o;
    }
}

// ===================== pooling =====================

__global__ void segstart_kernel(const int* __restrict__ batch, int* __restrict__ seg, int N, int G) {
    int g = blockIdx.x * blockDim.x + threadIdx.x;
    if (g > G) return;
    if (g == G) { seg[G] = N; return; }
    int lo = 0, hi = N;
    while (lo < hi) { int mid = (lo + hi) >> 1; if (batch[mid] < g) lo = mid + 1; else hi = mid; }
    seg[g] = lo;
}

__global__ void pool_kernel(const float* __restrict__ h,
                            const int* __restrict__ seg,
                            float* __restrict__ pooled,
                            int G) {
    int idx = blockIdx.x * blockDim.x + threadIdx.x;  // G * 9
    if (idx >= G * 9) return;
    int g = idx / 9;
    int t = idx - g * 9;
    int lo = seg[g], hi = seg[g + 1];
    float4 acc = make_float4(0.f, 0.f, 0.f, 0.f);
    for (int n = lo; n < hi; ++n) {
        float4 v = *reinterpret_cast<const float4*>(h + (long long)n * 36 + 4 * t);
        acc.x += v.x; acc.y += v.y; acc.z += v.z; acc.w += v.w;
    }
    *reinterpret_cast<float4*>(pooled + (long long)g * 36 + 4 * t) = acc;
}

// ===================== MLP head =====================

__global__ void mlp1_kernel(const float* __restrict__ pooled,
                            const float* __restrict__ lw1,
                            const float* __restrict__ lb1,
                            float* __restrict__ y1,
                            int G) {
    __shared__ float Ws[36 * 96];
    for (int i = threadIdx.x; i < 36 * 96; i += blockDim.x) Ws[i] = lw1[i];
    __syncthreads();
    int idx = blockIdx.x * blockDim.x + threadIdx.x;
    if (idx >= G * 96) return;
    int g = idx / 96;
    int j = idx - g * 96;
    const float* pr = pooled + (long long)g * 36;
    float acc = lb1[j];
#pragma unroll
    for (int k4 = 0; k4 < 9; ++k4) {
        float4 pv = *reinterpret_cast<const float4*>(pr + 4 * k4);
        acc += pv.x * Ws[(4 * k4 + 0) * 96 + j];
        acc += pv.y * Ws[(4 * k4 + 1) * 96 + j];
        acc += pv.z * Ws[(4 * k4 + 2) * 96 + j];
        acc += pv.w * Ws[(4 * k4 + 3) * 96 + j];
    }
    y1[idx] = fmaxf(acc, 0.0f);
}

__global__ void mlp2_kernel(const float* __restrict__ y1,
                            const float* __restrict__ lw2,
                            const float* __restrict__ lb2,
                            float* __restrict__ out,
                            int G) {
    __shared__ float Ws[96 * 27];
    for (int i = threadIdx.x; i < 96 * 27; i += blockDim.x) Ws[i] = lw2[i];
    __syncthreads();
    int idx = blockIdx.x * blockDim.x + threadIdx.x;
    if (idx >= G * 27) return;
    int g = idx / 27;
    int c = idx - g * 27;
    const float* yr = y1 + (long long)g * 96;
    float acc = lb2[c];
#pragma unroll
    for (int k4 = 0; k4 < 24; ++k4) {
        float4 yv = *reinterpret_cast<const float4*>(yr + 4 * k4);
        acc += yv.x * Ws[(4 * k4 + 0) * 27 + c];
        acc += yv.y * Ws[(4 * k4 + 1) * 27 + c];
        acc += yv.z * Ws[(4 * k4 + 2) * 27 + c];
        acc += yv.w * Ws[(4 * k4 + 3) * 27 + c];
    }
    out[idx] = fmaxf(acc, 0.0f);
}

// ===================== launch =====================

extern "C" void kernel_launch(void* const* d_in, const int* in_sizes, int n_in,
                              void* d_out, int out_size, void* d_ws, size_t ws_size,
                              hipStream_t stream) {
    const float* x     = (const float*)d_in[0];
    const int*   ei    = (const int*)d_in[1];
    const int*   batch = (const int*)d_in[2];
    const float* W1  = (const float*)d_in[4];
    const float* b1  = (const float*)d_in[5];
    const float* W2  = (const float*)d_in[6];
    const float* b2  = (const float*)d_in[7];
    const float* W3  = (const float*)d_in[8];
    const float* b3  = (const float*)d_in[9];
    const float* W4  = (const float*)d_in[10];
    const float* b4  = (const float*)d_in[11];
    const float* lw1 = (const float*)d_in[12];
    const float* lb1 = (const float*)d_in[13];
    const float* lw2 = (const float*)d_in[14];
    const float* lb2 = (const float*)d_in[15];
    float* out = (float*)d_out;

    const int N = in_sizes[0] / 75;
    const int E = in_sizes[1] / 2;
    const int G = out_size / 27;
    const int* srcp = ei;
    const int* dstp = ei + E;

    char* ws = (char*)d_ws;
    size_t off = 0;
    auto carve = [&](size_t bytes) -> char* {
        char* p = ws + off;
        off = (off + bytes + 255) & ~(size_t)255;
        return p;
    };
    int*    cnt        = (int*)carve((size_t)N * 4);
    int*    row_ptr    = (int*)carve((size_t)(N + 1) * 4);
    int*    sorted_src = (int*)carve((size_t)E * 4);
    int*    bsum       = (int*)carve((size_t)cdiv(N, 1024) * 4 + 4);
    int*    seg        = (int*)carve((size_t)(G + 1) * 4);
    float*  dinv       = (float*)carve((size_t)N * 4);
    char*   Abuf       = carve((size_t)N * 36 * 4);   // also ebuf (E*8 = 32MB <= 144MB)
    char*   Bbuf       = carve((size_t)N * 36 * 4);   // also HB (nblk*256*4 ~ 1MB)
    float*  pooled     = (float*)carve((size_t)G * 36 * 4);
    float*  y1         = (float*)carve((size_t)G * 96 * 4);
    (void)ws_size; (void)n_in;

    const int BLK = 256;
    const int nb = cdiv(N, 1024);
    const int nblk = cdiv(E, BUK_EDGES);
    int shift = 0;
    while (((long long)(N - 1) >> shift) >= NBUK) ++shift;

    int2* ebuf = (int2*)Abuf;
    int*  HB   = (int*)Bbuf;

    // ---- edge bucketing: count -> colscan -> scatter ----
    buk_count_kernel<<<nblk, NBUK, 0, stream>>>(dstp, HB, E, shift);
    buk_colscan_kernel<<<1, 1024, 0, stream>>>(HB, nblk);
    buk_scatter_kernel<<<nblk, NBUK, 0, stream>>>(srcp, dstp, HB, ebuf, E, shift);

    // ---- localized histogram -> dinv -> row_ptr scan -> localized CSR fill ----
    zero_int_kernel<<<cdiv(N, BLK), BLK, 0, stream>>>(cnt, N);
    hist_ebuf_kernel<<<cdiv(cdiv(E, 4), BLK), BLK, 0, stream>>>(ebuf, cnt, E);
    dinv_kernel<<<cdiv(N, BLK), BLK, 0, stream>>>(cnt, dinv, N);
    scan_partial_kernel<<<nb, 256, 0, stream>>>(cnt, bsum, N);
    if (nb <= 1024) scan_bsum_par_kernel<<<1, 1024, 0, stream>>>(bsum, nb);
    else            scan_bsum_serial_kernel<<<1, 64, 0, stream>>>(bsum, nb);
    scan_final_kernel<<<nb, 256, 0, stream>>>(cnt, bsum, row_ptr, N, E);
    zero_int_kernel<<<cdiv(N, BLK), BLK, 0, stream>>>(cnt, N);  // cursor = 0
    fill_ebuf_kernel<<<cdiv(cdiv(E, 4), BLK), BLK, 0, stream>>>(ebuf, row_ptr, cnt, sorted_src, E);
    segstart_kernel<<<cdiv(G + 1, BLK), BLK, 0, stream>>>(batch, seg, N, G);

    // fp16 u strides (halves): u1=16 (32B), u2=32 (64B line), u3=32 (64B line), u4=40 (80B)
    __half* u1 = (__half*)Bbuf;
    __half* u2 = (__half*)Abuf;   // ebuf no longer needed after fill
    __half* u3 = (__half*)Bbuf;
    __half* u4 = (__half*)Abuf;
    float*  h4 = (float*)Bbuf;

    gemm_scale_kernel<75, 15, 16><<<cdiv(N, BLK), BLK, 0, stream>>>(x, W1, dinv, u1, N);
    agg_gemm_kernel<16, 15, 20, 32><<<cdiv(N, BLK), BLK, 0, stream>>>(u1, row_ptr, sorted_src, dinv, b1, W2, u2, N);
    agg_gemm_kernel<32, 20, 27, 32><<<cdiv(N, BLK), BLK, 0, stream>>>(u2, row_ptr, sorted_src, dinv, b2, W3, u3, N);
    agg_gemm_kernel<32, 27, 36, 40><<<cdiv(N, BLK), BLK, 0, stream>>>(u3, row_ptr, sorted_src, dinv, b3, W4, u4, N);
    agg_selu_kernel<40, 36><<<cdiv(N, BLK), BLK, 0, stream>>>(u4, row_ptr, sorted_src, dinv, b4, h4, N);

    // ---- pool: segmented sum (batch_vec is sorted) ----
    pool_kernel<<<cdiv((long long)G * 9, BLK), BLK, 0, stream>>>(h4, seg, pooled, G);

    // ---- MLP head ----
    mlp1_kernel<<<cdiv((long long)G * 96, BLK), BLK, 0, stream>>>(pooled, lw1, lb1, y1, G);
    mlp2_kernel<<<cdiv((long long)G * 27, BLK), BLK, 0, stream>>>(y1, lw2, lb2, out, G);
}

// Round 12
// 901.061 us; speedup vs baseline: 10.4329x; 1.3231x over previous
//
#include <hip/hip_runtime.h>
#include <hip/hip_fp16.h>
#include <math.h>

#define SELU_SCALE 1.0507009873554805f
#define SELU_ALPHA 1.6732632423543772f

static inline int cdiv(long long a, int b) { return (int)((a + b - 1) / b); }

// packed fp16 max (v_pk_max_f16) — __hmax2 intrinsic is missing on this ROCm
__device__ __forceinline__ __half2 hmax2(__half2 a, __half2 b) {
    __half2 r;
    asm("v_pk_max_f16 %0, %1, %2" : "=v"(r) : "v"(a), "v"(b));
    return r;
}

// ===================== edge bucketing (256 coarse buckets by dst>>shift) =====================

#define NBUK 256
#define BUK_EDGES 4096  // edges per block (256 threads x 16)
#define NPB 4096        // nodes per bucket (shift = 12)

__global__ void buk_count_kernel(const int* __restrict__ dst, int* __restrict__ HB,
                                 int E, int shift) {
    __shared__ int lh[NBUK];
    int t = threadIdx.x;
    lh[t] = 0;
    __syncthreads();
    int e0 = blockIdx.x * BUK_EDGES + t * 16;
#pragma unroll
    for (int k = 0; k < 16; k += 4) {
        int e = e0 + k;
        if (e + 3 < E) {
            int4 d = *reinterpret_cast<const int4*>(dst + e);
            atomicAdd(&lh[d.x >> shift], 1);
            atomicAdd(&lh[d.y >> shift], 1);
            atomicAdd(&lh[d.z >> shift], 1);
            atomicAdd(&lh[d.w >> shift], 1);
        } else {
            for (int q = e; q < E && q < e + 4; ++q) atomicAdd(&lh[dst[q] >> shift], 1);
        }
    }
    __syncthreads();
    HB[blockIdx.x * NBUK + t] = lh[t];
}

// single block, 1024 threads = 4 chunks x 256 buckets; exclusive column scan + bucket base.
// After this, HB[0][b] = global edge start of bucket b.
__global__ void buk_colscan_kernel(int* __restrict__ HB, int nblk) {
    __shared__ int C[4 * NBUK];
    __shared__ int tot[NBUK];
    __shared__ int base[NBUK];
    int t = threadIdx.x;
    int chunk = t >> 8;
    int b = t & 255;
    int per = (nblk + 3) / 4;
    int k0 = chunk * per;
    int k1 = (k0 + per < nblk) ? k0 + per : nblk;
    int acc = 0;
    for (int k = k0; k < k1; ++k) {
        int v = HB[(long long)k * NBUK + b];
        HB[(long long)k * NBUK + b] = acc;
        acc += v;
    }
    C[chunk * NBUK + b] = acc;
    __syncthreads();
    if (chunk == 0) {
        int a = 0;
#pragma unroll
        for (int c = 0; c < 4; ++c) { int v = C[c * NBUK + b]; C[c * NBUK + b] = a; a += v; }
        tot[b] = a;
    }
    __syncthreads();
    if (t == 0) {
        int a = 0;
        for (int i = 0; i < NBUK; ++i) { base[i] = a; a += tot[i]; }
    }
    __syncthreads();
    int add = base[b] + C[chunk * NBUK + b];
    for (int k = k0; k < k1; ++k) HB[(long long)k * NBUK + b] += add;
}

__global__ void buk_scatter_kernel(const int* __restrict__ src, const int* __restrict__ dst,
                                   const int* __restrict__ HB, int2* __restrict__ ebuf,
                                   int E, int shift) {
    __shared__ int cur[NBUK];
    int t = threadIdx.x;
    cur[t] = HB[blockIdx.x * NBUK + t];
    __syncthreads();
    int e0 = blockIdx.x * BUK_EDGES + t * 16;
#pragma unroll
    for (int k = 0; k < 16; k += 4) {
        int e = e0 + k;
        if (e + 3 < E) {
            int4 d = *reinterpret_cast<const int4*>(dst + e);
            int4 s = *reinterpret_cast<const int4*>(src + e);
            int p0 = atomicAdd(&cur[d.x >> shift], 1);
            int p1 = atomicAdd(&cur[d.y >> shift], 1);
            int p2 = atomicAdd(&cur[d.z >> shift], 1);
            int p3 = atomicAdd(&cur[d.w >> shift], 1);
            ebuf[p0] = make_int2(s.x, d.x);
            ebuf[p1] = make_int2(s.y, d.y);
            ebuf[p2] = make_int2(s.z, d.z);
            ebuf[p3] = make_int2(s.w, d.w);
        } else {
            for (int q = e; q < E && q < e + 4; ++q) {
                int dd = dst[q];
                int p = atomicAdd(&cur[dd >> shift], 1);
                ebuf[p] = make_int2(src[q], dd);
            }
        }
    }
}

// ===================== fused per-bucket CSR build (zero global atomics) =====================
// One block per bucket: LDS hist -> LDS scan -> row_ptr/dinv write (coalesced)
// -> LDS-cursor fill of sorted_src. All atomics are LDS-scope.
__global__ void bucket_csr_kernel(const int2* __restrict__ ebuf, const int* __restrict__ HB,
                                  int* __restrict__ row_ptr, float* __restrict__ dinv,
                                  int* __restrict__ sorted_src, int N, int E, int shift) {
    __shared__ int lhist[NPB];
    __shared__ int lscan[NPB];
    __shared__ int psum[256];
    int b = blockIdx.x;
    int t = threadIdx.x;
    int nbase = b << shift;
    int eb0 = HB[b];
    int eb1 = (b + 1 < NBUK) ? HB[b + 1] : E;

    // 1. zero hist
    for (int i = t; i < NPB; i += 256) lhist[i] = 0;
    __syncthreads();
    // 2. LDS histogram of this bucket's edges
    for (int e = eb0 + t; e < eb1; e += 256) {
        int2 ed = ebuf[e];
        atomicAdd(&lhist[ed.y - nbase], 1);
    }
    __syncthreads();
    // 3. per-thread partial sums (16 entries each) + block exclusive scan
    {
        int s = 0;
#pragma unroll
        for (int k = 0; k < 16; ++k) s += lhist[t * 16 + k];
        psum[t] = s;
        __syncthreads();
        // inclusive ladder
        for (int o = 1; o < 256; o <<= 1) {
            int y = (t >= o) ? psum[t - o] : 0;
            __syncthreads();
            psum[t] += y;
            __syncthreads();
        }
        int run = psum[t] - s;  // exclusive
#pragma unroll
        for (int k = 0; k < 16; ++k) {
            int i = t * 16 + k;
            lscan[i] = run;
            run += lhist[i];
        }
    }
    __syncthreads();
    // 4. coalesced row_ptr + dinv writes
    for (int i = t; i < NPB; i += 256) {
        int n = nbase + i;
        if (n < N) {
            row_ptr[n] = eb0 + lscan[i];
            dinv[n] = rsqrtf((float)lhist[i] + 1.0f);
        }
    }
    if (b == 0 && t == 0) row_ptr[N] = E;
    __syncthreads();
    // 5. reset hist -> cursor
    for (int i = t; i < NPB; i += 256) lhist[i] = 0;
    __syncthreads();
    // 6. fill sorted_src (writes localized to this bucket's 64KB window)
    for (int e = eb0 + t; e < eb1; e += 256) {
        int2 ed = ebuf[e];
        int nd = ed.y - nbase;
        int pos = eb0 + lscan[nd] + atomicAdd(&lhist[nd], 1);
        sorted_src[pos] = ed.x;
    }
}

// ===================== fp16 row helpers (packed half2) =====================

template <int SH>
__device__ __forceinline__ void load_row_h2(__half2* __restrict__ acc, const __half* __restrict__ row) {
#pragma unroll
    for (int u = 0; u < SH / 8; ++u) {
        union { float4 f4; __half2 h2[4]; } ld;
        ld.f4 = *reinterpret_cast<const float4*>(row + u * 8);
#pragma unroll
        for (int k = 0; k < 4; ++k) acc[u * 4 + k] = ld.h2[k];
    }
}

template <int SH>
__device__ __forceinline__ void fmax_row_h2(__half2* __restrict__ acc, const __half* __restrict__ row) {
#pragma unroll
    for (int u = 0; u < SH / 8; ++u) {
        union { float4 f4; __half2 h2[4]; } ld;
        ld.f4 = *reinterpret_cast<const float4*>(row + u * 8);
#pragma unroll
        for (int k = 0; k < 4; ++k) acc[u * 4 + k] = hmax2(acc[u * 4 + k], ld.h2[k]);
    }
}

template <int FOUT, int SOUTH>
__device__ __forceinline__ void store_row_h(__half* __restrict__ op,
                                            const float* __restrict__ vals, float dv) {
#pragma unroll
    for (int u = 0; u < SOUTH / 8; ++u) {
        union { float4 f4; __half2 h2[4]; } pk;
#pragma unroll
        for (int k = 0; k < 4; ++k) {
            int f0 = u * 8 + 2 * k, f1 = f0 + 1;
            float a = (f0 < FOUT) ? vals[(f0 < FOUT) ? f0 : 0] * dv : 0.0f;
            float b = (f1 < FOUT) ? vals[(f1 < FOUT) ? f1 : 0] * dv : 0.0f;
            pk.h2[k] = __floats2half2_rn(a, b);
        }
        *reinterpret_cast<float4*>(op + u * 8) = pk.f4;
    }
}

// neighbor max loop, unroll-4 (4 independent row loads in flight)
template <int SH>
__device__ __forceinline__ void gather_max_loop(__half2* __restrict__ acc,
                                                const __half* __restrict__ u,
                                                const int* __restrict__ sorted_src,
                                                int j0, int j1) {
    int j = j0;
    for (; j + 4 <= j1; j += 4) {
        int s0 = sorted_src[j + 0];
        int s1 = sorted_src[j + 1];
        int s2 = sorted_src[j + 2];
        int s3 = sorted_src[j + 3];
        fmax_row_h2<SH>(acc, u + (long long)s0 * SH);
        fmax_row_h2<SH>(acc, u + (long long)s1 * SH);
        fmax_row_h2<SH>(acc, u + (long long)s2 * SH);
        fmax_row_h2<SH>(acc, u + (long long)s3 * SH);
    }
    for (; j < j1; ++j) fmax_row_h2<SH>(acc, u + (long long)sorted_src[j] * SH);
}

// ===================== layer kernels =====================

// layer-1 GEMM: u1[n,:] = half((x[n,:] @ W1) * dinv[n])
template <int FIN, int FOUT, int SOUTH>
__global__ void gemm_scale_kernel(const float* __restrict__ h,
                                  const float* __restrict__ W,
                                  const float* __restrict__ dinv,
                                  __half* __restrict__ u,
                                  int N) {
    int n = blockIdx.x * blockDim.x + threadIdx.x;
    if (n >= N) return;
    const float* hr = h + (long long)n * FIN;
    float acc[FOUT];
#pragma unroll
    for (int c = 0; c < FOUT; ++c) acc[c] = 0.0f;
#pragma unroll
    for (int fi = 0; fi < FIN; ++fi) {
        float hv = hr[fi];
#pragma unroll
        for (int c = 0; c < FOUT; ++c) acc[c] += hv * W[fi * FOUT + c];
    }
    store_row_h<FOUT, SOUTH>(u + (long long)n * SOUTH, acc, dinv[n]);
}

// fused agg + next-layer GEMM, thread per node
template <int SPREVH, int FPREV, int FOUT, int SOUTH>
__global__ void agg_gemm_kernel(const __half* __restrict__ u,
                                const int* __restrict__ row_ptr,
                                const int* __restrict__ sorted_src,
                                const float* __restrict__ dinv,
                                const float* __restrict__ bprev,
                                const float* __restrict__ W,
                                __half* __restrict__ uout,
                                int N) {
    int n = blockIdx.x * blockDim.x + threadIdx.x;
    if (n >= N) return;
    __half2 acc[SPREVH / 2];
    load_row_h2<SPREVH>(acc, u + (long long)n * SPREVH);  // self loop
    int j0 = row_ptr[n], j1 = row_ptr[n + 1];
    gather_max_loop<SPREVH>(acc, u, sorted_src, j0, j1);

    float af[SPREVH];
#pragma unroll
    for (int i = 0; i < SPREVH / 2; ++i) {
        float2 p = __half22float2(acc[i]);
        af[2 * i] = p.x;
        af[2 * i + 1] = p.y;
    }
    float dv = dinv[n];
    float h[FPREV];
#pragma unroll
    for (int f = 0; f < FPREV; ++f) {
        float v = dv * af[f] + bprev[f];
        h[f] = (v > 0.0f) ? (SELU_SCALE * v) : (SELU_SCALE * SELU_ALPHA * (expf(v) - 1.0f));
    }
    float outv[FOUT];
#pragma unroll
    for (int c = 0; c < FOUT; ++c) outv[c] = 0.0f;
#pragma unroll
    for (int fi = 0; fi < FPREV; ++fi) {
        float hv = h[fi];
#pragma unroll
        for (int c = 0; c < FOUT; ++c) outv[c] += hv * W[fi * FOUT + c];
    }
    store_row_h<FOUT, SOUTH>(uout + (long long)n * SOUTH, outv, dv);
}

// final aggregation (layer 4): fp32 output stride F
template <int SH, int F>
__global__ void agg_selu_kernel(const __half* __restrict__ u,
                                const int* __restrict__ row_ptr,
                                const int* __restrict__ sorted_src,
                                const float* __restrict__ dinv,
                                const float* __restrict__ b,
                                float* __restrict__ hout,
                                int N) {
    int n = blockIdx.x * blockDim.x + threadIdx.x;
    if (n >= N) return;
    __half2 acc[SH / 2];
    load_row_h2<SH>(acc, u + (long long)n * SH);
    int j0 = row_ptr[n], j1 = row_ptr[n + 1];
    gather_max_loop<SH>(acc, u, sorted_src, j0, j1);

    float dv = dinv[n];
    float* op = hout + (long long)n * F;
#pragma unroll
    for (int q = 0; q < F / 4; ++q) {
        float4 o;
        float* ov = &o.x;
#pragma unroll
        for (int k = 0; k < 4; ++k) {
            int f = 4 * q + k;
            float2 p = __half22float2(acc[f / 2]);
            float raw = (f & 1) ? p.y : p.x;
            float v = dv * raw + b[f];
            ov[k] = (v > 0.0f) ? (SELU_SCALE * v) : (SELU_SCALE * SELU_ALPHA * (expf(v) - 1.0f));
        }
        *reinterpret_cast<float4*>(op + 4 * q) = o;
    }
}

// ===================== pooling =====================

__global__ void segstart_kernel(const int* __restrict__ batch, int* __restrict__ seg, int N, int G) {
    int g = blockIdx.x * blockDim.x + threadIdx.x;
    if (g > G) return;
    if (g == G) { seg[G] = N; return; }
    int lo = 0, hi = N;
    while (lo < hi) { int mid = (lo + hi) >> 1; if (batch[mid] < g) lo = mid + 1; else hi = mid; }
    seg[g] = lo;
}

__global__ void pool_kernel(const float* __restrict__ h,
                            const int* __restrict__ seg,
                            float* __restrict__ pooled,
                            int G) {
    int idx = blockIdx.x * blockDim.x + threadIdx.x;  // G * 9
    if (idx >= G * 9) return;
    int g = idx / 9;
    int t = idx - g * 9;
    int lo = seg[g], hi = seg[g + 1];
    float4 acc = make_float4(0.f, 0.f, 0.f, 0.f);
    for (int n = lo; n < hi; ++n) {
        float4 v = *reinterpret_cast<const float4*>(h + (long long)n * 36 + 4 * t);
        acc.x += v.x; acc.y += v.y; acc.z += v.z; acc.w += v.w;
    }
    *reinterpret_cast<float4*>(pooled + (long long)g * 36 + 4 * t) = acc;
}

// ===================== MLP head =====================

__global__ void mlp1_kernel(const float* __restrict__ pooled,
                            const float* __restrict__ lw1,
                            const float* __restrict__ lb1,
                            float* __restrict__ y1,
                            int G) {
    __shared__ float Ws[36 * 96];
    for (int i = threadIdx.x; i < 36 * 96; i += blockDim.x) Ws[i] = lw1[i];
    __syncthreads();
    int idx = blockIdx.x * blockDim.x + threadIdx.x;
    if (idx >= G * 96) return;
    int g = idx / 96;
    int j = idx - g * 96;
    const float* pr = pooled + (long long)g * 36;
    float acc = lb1[j];
#pragma unroll
    for (int k4 = 0; k4 < 9; ++k4) {
        float4 pv = *reinterpret_cast<const float4*>(pr + 4 * k4);
        acc += pv.x * Ws[(4 * k4 + 0) * 96 + j];
        acc += pv.y * Ws[(4 * k4 + 1) * 96 + j];
        acc += pv.z * Ws[(4 * k4 + 2) * 96 + j];
        acc += pv.w * Ws[(4 * k4 + 3) * 96 + j];
    }
    y1[idx] = fmaxf(acc, 0.0f);
}

__global__ void mlp2_kernel(const float* __restrict__ y1,
                            const float* __restrict__ lw2,
                            const float* __restrict__ lb2,
                            float* __restrict__ out,
                            int G) {
    __shared__ float Ws[96 * 27];
    for (int i = threadIdx.x; i < 96 * 27; i += blockDim.x) Ws[i] = lw2[i];
    __syncthreads();
    int idx = blockIdx.x * blockDim.x + threadIdx.x;
    if (idx >= G * 27) return;
    int g = idx / 27;
    int c = idx - g * 27;
    const float* yr = y1 + (long long)g * 96;
    float acc = lb2[c];
#pragma unroll
    for (int k4 = 0; k4 < 24; ++k4) {
        float4 yv = *reinterpret_cast<const float4*>(yr + 4 * k4);
        acc += yv.x * Ws[(4 * k4 + 0) * 27 + c];
        acc += yv.y * Ws[(4 * k4 + 1) * 27 + c];
        acc += yv.z * Ws[(4 * k4 + 2) * 27 + c];
        acc += yv.w * Ws[(4 * k4 + 3) * 27 + c];
    }
    out[idx] = fmaxf(acc, 0.0f);
}

// ===================== launch =====================

extern "C" void kernel_launch(void* const* d_in, const int* in_sizes, int n_in,
                              void* d_out, int out_size, void* d_ws, size_t ws_size,
                              hipStream_t stream) {
    const float* x     = (const float*)d_in[0];
    const int*   ei    = (const int*)d_in[1];
    const int*   batch = (const int*)d_in[2];
    const float* W1  = (const float*)d_in[4];
    const float* b1  = (const float*)d_in[5];
    const float* W2  = (const float*)d_in[6];
    const float* b2  = (const float*)d_in[7];
    const float* W3  = (const float*)d_in[8];
    const float* b3  = (const float*)d_in[9];
    const float* W4  = (const float*)d_in[10];
    const float* b4  = (const float*)d_in[11];
    const float* lw1 = (const float*)d_in[12];
    const float* lb1 = (const float*)d_in[13];
    const float* lw2 = (const float*)d_in[14];
    const float* lb2 = (const float*)d_in[15];
    float* out = (float*)d_out;

    const int N = in_sizes[0] / 75;
    const int E = in_sizes[1] / 2;
    const int G = out_size / 27;
    const int* srcp = ei;
    const int* dstp = ei + E;

    char* ws = (char*)d_ws;
    size_t off = 0;
    auto carve = [&](size_t bytes) -> char* {
        char* p = ws + off;
        off = (off + bytes + 255) & ~(size_t)255;
        return p;
    };
    int*    row_ptr    = (int*)carve((size_t)(N + 1) * 4);
    int*    sorted_src = (int*)carve((size_t)E * 4);
    int*    seg        = (int*)carve((size_t)(G + 1) * 4);
    float*  dinv       = (float*)carve((size_t)N * 4);
    char*   Abuf       = carve((size_t)N * 36 * 4);   // also ebuf (E*8 = 32MB <= 144MB)
    char*   Bbuf       = carve((size_t)N * 36 * 4);   // also HB (nblk*256*4 ~ 1MB)
    float*  pooled     = (float*)carve((size_t)G * 36 * 4);
    float*  y1         = (float*)carve((size_t)G * 96 * 4);
    (void)ws_size; (void)n_in;

    const int BLK = 256;
    const int nblk = cdiv(E, BUK_EDGES);
    int shift = 0;
    while (((long long)(N - 1) >> shift) >= NBUK) ++shift;  // N=1e6 -> 12 (NPB=4096)

    int2* ebuf = (int2*)Abuf;
    int*  HB   = (int*)Bbuf;

    // ---- edge bucketing: count -> colscan -> scatter ----
    buk_count_kernel<<<nblk, NBUK, 0, stream>>>(dstp, HB, E, shift);
    buk_colscan_kernel<<<1, 1024, 0, stream>>>(HB, nblk);
    buk_scatter_kernel<<<nblk, NBUK, 0, stream>>>(srcp, dstp, HB, ebuf, E, shift);

    // ---- fused per-bucket CSR build (no global atomics) ----
    bucket_csr_kernel<<<NBUK, 256, 0, stream>>>(ebuf, HB, row_ptr, dinv, sorted_src, N, E, shift);
    segstart_kernel<<<cdiv(G + 1, BLK), BLK, 0, stream>>>(batch, seg, N, G);

    // fp16 u strides (halves): u1=16 (32B), u2=32 (64B line), u3=32 (64B line), u4=40 (80B)
    __half* u1 = (__half*)Bbuf;   // HB dead after bucket_csr
    __half* u2 = (__half*)Abuf;   // ebuf dead after bucket_csr
    __half* u3 = (__half*)Bbuf;
    __half* u4 = (__half*)Abuf;
    float*  h4 = (float*)Bbuf;

    gemm_scale_kernel<75, 15, 16><<<cdiv(N, BLK), BLK, 0, stream>>>(x, W1, dinv, u1, N);
    agg_gemm_kernel<16, 15, 20, 32><<<cdiv(N, BLK), BLK, 0, stream>>>(u1, row_ptr, sorted_src, dinv, b1, W2, u2, N);
    agg_gemm_kernel<32, 20, 27, 32><<<cdiv(N, BLK), BLK, 0, stream>>>(u2, row_ptr, sorted_src, dinv, b2, W3, u3, N);
    agg_gemm_kernel<32, 27, 36, 40><<<cdiv(N, BLK), BLK, 0, stream>>>(u3, row_ptr, sorted_src, dinv, b3, W4, u4, N);
    agg_selu_kernel<40, 36><<<cdiv(N, BLK), BLK, 0, stream>>>(u4, row_ptr, sorted_src, dinv, b4, h4, N);

    // ---- pool: segmented sum (batch_vec is sorted) ----
    pool_kernel<<<cdiv((long long)G * 9, BLK), BLK, 0, stream>>>(h4, seg, pooled, G);

    // ---- MLP head ----
    mlp1_kernel<<<cdiv((long long)G * 96, BLK), BLK, 0, stream>>>(pooled, lw1, lb1, y1, G);
    mlp2_kernel<<<cdiv((long long)G * 27, BLK), BLK, 0, stream>>>(y1, lw2, lb2, out, G);
}

// Round 13
// 861.335 us; speedup vs baseline: 10.9141x; 1.0461x over previous
//
#include <hip/hip_runtime.h>
#include <hip/hip_fp16.h>
#include <math.h>

#define SELU_SCALE 1.0507009873554805f
#define SELU_ALPHA 1.6732632423543772f

static inline int cdiv(long long a, int b) { return (int)((a + b - 1) / b); }

// packed fp16 max (v_pk_max_f16) — __hmax2 intrinsic is missing on this ROCm
__device__ __forceinline__ __half2 hmax2(__half2 a, __half2 b) {
    __half2 r;
    asm("v_pk_max_f16 %0, %1, %2" : "=v"(r) : "v"(a), "v"(b));
    return r;
}

// ===================== edge bucketing (256 coarse buckets by dst>>shift) =====================
// ebuf entry packed in 32 bits: src (low 20 bits, N < 2^20) | bucket-local dst (high 12 bits).

#define NBUK 256
#define BUK_EDGES 4096  // edges per block (256 threads x 16)
#define NPB 4096        // max nodes per bucket (shift <= 12)
#define SRC_BITS 20
#define SRC_MASK ((1 << SRC_BITS) - 1)

__global__ void buk_count_kernel(const int* __restrict__ dst, int* __restrict__ HB,
                                 int E, int shift) {
    __shared__ int lh[NBUK];
    int t = threadIdx.x;
    lh[t] = 0;
    __syncthreads();
    int e0 = blockIdx.x * BUK_EDGES + t * 16;
#pragma unroll
    for (int k = 0; k < 16; k += 4) {
        int e = e0 + k;
        if (e + 3 < E) {
            int4 d = *reinterpret_cast<const int4*>(dst + e);
            atomicAdd(&lh[d.x >> shift], 1);
            atomicAdd(&lh[d.y >> shift], 1);
            atomicAdd(&lh[d.z >> shift], 1);
            atomicAdd(&lh[d.w >> shift], 1);
        } else {
            for (int q = e; q < E && q < e + 4; ++q) atomicAdd(&lh[dst[q] >> shift], 1);
        }
    }
    __syncthreads();
    HB[blockIdx.x * NBUK + t] = lh[t];
}

// single block, 1024 threads = 4 chunks x 256 buckets; exclusive column scan + bucket base.
// After this, HB[0][b] = global edge start of bucket b.
__global__ void buk_colscan_kernel(int* __restrict__ HB, int nblk) {
    __shared__ int C[4 * NBUK];
    __shared__ int tot[NBUK];
    __shared__ int base[NBUK];
    int t = threadIdx.x;
    int chunk = t >> 8;
    int b = t & 255;
    int per = (nblk + 3) / 4;
    int k0 = chunk * per;
    int k1 = (k0 + per < nblk) ? k0 + per : nblk;
    int acc = 0;
    for (int k = k0; k < k1; ++k) {
        int v = HB[(long long)k * NBUK + b];
        HB[(long long)k * NBUK + b] = acc;
        acc += v;
    }
    C[chunk * NBUK + b] = acc;
    __syncthreads();
    if (chunk == 0) {
        int a = 0;
#pragma unroll
        for (int c = 0; c < 4; ++c) { int v = C[c * NBUK + b]; C[c * NBUK + b] = a; a += v; }
        tot[b] = a;
    }
    __syncthreads();
    if (t == 0) {
        int a = 0;
        for (int i = 0; i < NBUK; ++i) { base[i] = a; a += tot[i]; }
    }
    __syncthreads();
    int add = base[b] + C[chunk * NBUK + b];
    for (int k = k0; k < k1; ++k) HB[(long long)k * NBUK + b] += add;
}

__global__ void buk_scatter_kernel(const int* __restrict__ src, const int* __restrict__ dst,
                                   const int* __restrict__ HB, int* __restrict__ ebuf,
                                   int E, int shift) {
    __shared__ int cur[NBUK];
    int t = threadIdx.x;
    cur[t] = HB[blockIdx.x * NBUK + t];
    __syncthreads();
    int lmask = (1 << shift) - 1;
    int e0 = blockIdx.x * BUK_EDGES + t * 16;
#pragma unroll
    for (int k = 0; k < 16; k += 4) {
        int e = e0 + k;
        if (e + 3 < E) {
            int4 d = *reinterpret_cast<const int4*>(dst + e);
            int4 s = *reinterpret_cast<const int4*>(src + e);
            int p0 = atomicAdd(&cur[d.x >> shift], 1);
            int p1 = atomicAdd(&cur[d.y >> shift], 1);
            int p2 = atomicAdd(&cur[d.z >> shift], 1);
            int p3 = atomicAdd(&cur[d.w >> shift], 1);
            ebuf[p0] = s.x | ((d.x & lmask) << SRC_BITS);
            ebuf[p1] = s.y | ((d.y & lmask) << SRC_BITS);
            ebuf[p2] = s.z | ((d.z & lmask) << SRC_BITS);
            ebuf[p3] = s.w | ((d.w & lmask) << SRC_BITS);
        } else {
            for (int q = e; q < E && q < e + 4; ++q) {
                int dd = dst[q];
                int p = atomicAdd(&cur[dd >> shift], 1);
                ebuf[p] = src[q] | ((dd & lmask) << SRC_BITS);
            }
        }
    }
}

// ===================== fused per-bucket CSR build (zero global atomics) =====================
__global__ void bucket_csr_kernel(const int* __restrict__ ebuf, const int* __restrict__ HB,
                                  int* __restrict__ row_ptr, float* __restrict__ dinv,
                                  int* __restrict__ sorted_src, int N, int E, int shift) {
    __shared__ int lhist[NPB];
    __shared__ int lscan[NPB];
    __shared__ int psum[256];
    int b = blockIdx.x;
    int t = threadIdx.x;
    int npb = 1 << shift;
    int nbase = b << shift;
    int eb0 = HB[b];
    int eb1 = (b + 1 < NBUK) ? HB[b + 1] : E;

    for (int i = t; i < npb; i += 256) lhist[i] = 0;
    __syncthreads();
    for (int e = eb0 + t; e < eb1; e += 256) {
        unsigned int pe = (unsigned int)ebuf[e];
        atomicAdd(&lhist[pe >> SRC_BITS], 1);
    }
    __syncthreads();
    // block exclusive scan over npb entries (each thread owns npb/256 entries)
    {
        int per = npb >> 8;  // npb is a power of two >= 256 here (shift >= 8 for N > 32768)
        int s = 0;
        for (int k = 0; k < per; ++k) s += lhist[t * per + k];
        psum[t] = s;
        __syncthreads();
        for (int o = 1; o < 256; o <<= 1) {
            int y = (t >= o) ? psum[t - o] : 0;
            __syncthreads();
            psum[t] += y;
            __syncthreads();
        }
        int run = psum[t] - s;  // exclusive
        for (int k = 0; k < per; ++k) {
            int i = t * per + k;
            lscan[i] = run;
            run += lhist[i];
        }
    }
    __syncthreads();
    for (int i = t; i < npb; i += 256) {
        int n = nbase + i;
        if (n < N) {
            row_ptr[n] = eb0 + lscan[i];
            dinv[n] = rsqrtf((float)lhist[i] + 1.0f);
        }
    }
    if (b == 0 && t == 0) row_ptr[N] = E;
    __syncthreads();
    for (int i = t; i < npb; i += 256) lhist[i] = 0;
    __syncthreads();
    for (int e = eb0 + t; e < eb1; e += 256) {
        unsigned int pe = (unsigned int)ebuf[e];
        int nd = pe >> SRC_BITS;
        int pos = eb0 + lscan[nd] + atomicAdd(&lhist[nd], 1);
        sorted_src[pos] = (int)(pe & SRC_MASK);
    }
}

// ===================== fp16 row helpers (packed half2) =====================

template <int SH>
__device__ __forceinline__ void load_row_h2(__half2* __restrict__ acc, const __half* __restrict__ row) {
#pragma unroll
    for (int u = 0; u < SH / 8; ++u) {
        union { float4 f4; __half2 h2[4]; } ld;
        ld.f4 = *reinterpret_cast<const float4*>(row + u * 8);
#pragma unroll
        for (int k = 0; k < 4; ++k) acc[u * 4 + k] = ld.h2[k];
    }
}

template <int SH>
__device__ __forceinline__ void fmax_row_h2(__half2* __restrict__ acc, const __half* __restrict__ row) {
#pragma unroll
    for (int u = 0; u < SH / 8; ++u) {
        union { float4 f4; __half2 h2[4]; } ld;
        ld.f4 = *reinterpret_cast<const float4*>(row + u * 8);
#pragma unroll
        for (int k = 0; k < 4; ++k) acc[u * 4 + k] = hmax2(acc[u * 4 + k], ld.h2[k]);
    }
}

template <int FOUT, int SOUTH>
__device__ __forceinline__ void store_row_h(__half* __restrict__ op,
                                            const float* __restrict__ vals, float dv) {
#pragma unroll
    for (int u = 0; u < SOUTH / 8; ++u) {
        union { float4 f4; __half2 h2[4]; } pk;
#pragma unroll
        for (int k = 0; k < 4; ++k) {
            int f0 = u * 8 + 2 * k, f1 = f0 + 1;
            float a = (f0 < FOUT) ? vals[(f0 < FOUT) ? f0 : 0] * dv : 0.0f;
            float b = (f1 < FOUT) ? vals[(f1 < FOUT) ? f1 : 0] * dv : 0.0f;
            pk.h2[k] = __floats2half2_rn(a, b);
        }
        *reinterpret_cast<float4*>(op + u * 8) = pk.f4;
    }
}

// neighbor max loop, unroll-4 (4 independent row loads in flight)
template <int SH>
__device__ __forceinline__ void gather_max_loop(__half2* __restrict__ acc,
                                                const __half* __restrict__ u,
                                                const int* __restrict__ sorted_src,
                                                int j0, int j1) {
    int j = j0;
    for (; j + 4 <= j1; j += 4) {
        int s0 = sorted_src[j + 0];
        int s1 = sorted_src[j + 1];
        int s2 = sorted_src[j + 2];
        int s3 = sorted_src[j + 3];
        fmax_row_h2<SH>(acc, u + (long long)s0 * SH);
        fmax_row_h2<SH>(acc, u + (long long)s1 * SH);
        fmax_row_h2<SH>(acc, u + (long long)s2 * SH);
        fmax_row_h2<SH>(acc, u + (long long)s3 * SH);
    }
    for (; j < j1; ++j) fmax_row_h2<SH>(acc, u + (long long)sorted_src[j] * SH);
}

// ===================== layer kernels =====================

// layer-1 GEMM: u1[n,:] = half((x[n,:] @ W1) * dinv[n])
template <int FIN, int FOUT, int SOUTH>
__global__ void gemm_scale_kernel(const float* __restrict__ h,
                                  const float* __restrict__ W,
                                  const float* __restrict__ dinv,
                                  __half* __restrict__ u,
                                  int N) {
    int n = blockIdx.x * blockDim.x + threadIdx.x;
    if (n >= N) return;
    const float* hr = h + (long long)n * FIN;
    float acc[FOUT];
#pragma unroll
    for (int c = 0; c < FOUT; ++c) acc[c] = 0.0f;
#pragma unroll
    for (int fi = 0; fi < FIN; ++fi) {
        float hv = hr[fi];
#pragma unroll
        for (int c = 0; c < FOUT; ++c) acc[c] += hv * W[fi * FOUT + c];
    }
    store_row_h<FOUT, SOUTH>(u + (long long)n * SOUTH, acc, dinv[n]);
}

// fused agg + next-layer GEMM, thread per node
template <int SPREVH, int FPREV, int FOUT, int SOUTH>
__global__ void agg_gemm_kernel(const __half* __restrict__ u,
                                const int* __restrict__ row_ptr,
                                const int* __restrict__ sorted_src,
                                const float* __restrict__ dinv,
                                const float* __restrict__ bprev,
                                const float* __restrict__ W,
                                __half* __restrict__ uout,
                                int N) {
    int n = blockIdx.x * blockDim.x + threadIdx.x;
    if (n >= N) return;
    __half2 acc[SPREVH / 2];
    load_row_h2<SPREVH>(acc, u + (long long)n * SPREVH);  // self loop
    int j0 = row_ptr[n], j1 = row_ptr[n + 1];
    gather_max_loop<SPREVH>(acc, u, sorted_src, j0, j1);

    float af[SPREVH];
#pragma unroll
    for (int i = 0; i < SPREVH / 2; ++i) {
        float2 p = __half22float2(acc[i]);
        af[2 * i] = p.x;
        af[2 * i + 1] = p.y;
    }
    float dv = dinv[n];
    float h[FPREV];
#pragma unroll
    for (int f = 0; f < FPREV; ++f) {
        float v = dv * af[f] + bprev[f];
        h[f] = (v > 0.0f) ? (SELU_SCALE * v) : (SELU_SCALE * SELU_ALPHA * (expf(v) - 1.0f));
    }
    float outv[FOUT];
#pragma unroll
    for (int c = 0; c < FOUT; ++c) outv[c] = 0.0f;
#pragma unroll
    for (int fi = 0; fi < FPREV; ++fi) {
        float hv = h[fi];
#pragma unroll
        for (int c = 0; c < FOUT; ++c) outv[c] += hv * W[fi * FOUT + c];
    }
    store_row_h<FOUT, SOUTH>(uout + (long long)n * SOUTH, outv, dv);
}

// final aggregation (layer 4): fp16 output stride SOUTH
template <int SH, int F, int SOUTH>
__global__ void agg_selu_kernel(const __half* __restrict__ u,
                                const int* __restrict__ row_ptr,
                                const int* __restrict__ sorted_src,
                                const float* __restrict__ dinv,
                                const float* __restrict__ b,
                                __half* __restrict__ hout,
                                int N) {
    int n = blockIdx.x * blockDim.x + threadIdx.x;
    if (n >= N) return;
    __half2 acc[SH / 2];
    load_row_h2<SH>(acc, u + (long long)n * SH);
    int j0 = row_ptr[n], j1 = row_ptr[n + 1];
    gather_max_loop<SH>(acc, u, sorted_src, j0, j1);

    float dv = dinv[n];
    float vals[F];
#pragma unroll
    for (int f = 0; f < F; ++f) {
        float2 p = __half22float2(acc[f / 2]);
        float raw = (f & 1) ? p.y : p.x;
        float v = dv * raw + b[f];
        vals[f] = (v > 0.0f) ? (SELU_SCALE * v) : (SELU_SCALE * SELU_ALPHA * (expf(v) - 1.0f));
    }
    store_row_h<F, SOUTH>(hout + (long long)n * SOUTH, vals, 1.0f);
}

// ===================== pooling (fp16 input, fp32 accumulate) =====================

__global__ void segstart_kernel(const int* __restrict__ batch, int* __restrict__ seg, int N, int G) {
    int g = blockIdx.x * blockDim.x + threadIdx.x;
    if (g > G) return;
    if (g == G) { seg[G] = N; return; }
    int lo = 0, hi = N;
    while (lo < hi) { int mid = (lo + hi) >> 1; if (batch[mid] < g) lo = mid + 1; else hi = mid; }
    seg[g] = lo;
}

#define H4S 40  // h4 stride in halves

__global__ void pool_kernel_h(const __half* __restrict__ h,
                              const int* __restrict__ seg,
                              float* __restrict__ pooled,
                              int G) {
    int idx = blockIdx.x * blockDim.x + threadIdx.x;  // G * 9
    if (idx >= G * 9) return;
    int g = idx / 9;
    int t = idx - g * 9;
    int lo = seg[g], hi = seg[g + 1];
    float4 acc = make_float4(0.f, 0.f, 0.f, 0.f);
    for (int n = lo; n < hi; ++n) {
        union { float2 f2; __half2 h2[2]; } ld;
        ld.f2 = *reinterpret_cast<const float2*>(h + (long long)n * H4S + 4 * t);
        float2 a = __half22float2(ld.h2[0]);
        float2 b = __half22float2(ld.h2[1]);
        acc.x += a.x; acc.y += a.y; acc.z += b.x; acc.w += b.y;
    }
    *reinterpret_cast<float4*>(pooled + (long long)g * 36 + 4 * t) = acc;
}

// ===================== MLP head =====================

__global__ void mlp1_kernel(const float* __restrict__ pooled,
                            const float* __restrict__ lw1,
                            const float* __restrict__ lb1,
                            float* __restrict__ y1,
                            int G) {
    __shared__ float Ws[36 * 96];
    for (int i = threadIdx.x; i < 36 * 96; i += blockDim.x) Ws[i] = lw1[i];
    __syncthreads();
    int idx = blockIdx.x * blockDim.x + threadIdx.x;
    if (idx >= G * 96) return;
    int g = idx / 96;
    int j = idx - g * 96;
    const float* pr = pooled + (long long)g * 36;
    float acc = lb1[j];
#pragma unroll
    for (int k4 = 0; k4 < 9; ++k4) {
        float4 pv = *reinterpret_cast<const float4*>(pr + 4 * k4);
        acc += pv.x * Ws[(4 * k4 + 0) * 96 + j];
        acc += pv.y * Ws[(4 * k4 + 1) * 96 + j];
        acc += pv.z * Ws[(4 * k4 + 2) * 96 + j];
        acc += pv.w * Ws[(4 * k4 + 3) * 96 + j];
    }
    y1[idx] = fmaxf(acc, 0.0f);
}

__global__ void mlp2_kernel(const float* __restrict__ y1,
                            const float* __restrict__ lw2,
                            const float* __restrict__ lb2,
                            float* __restrict__ out,
                            int G) {
    __shared__ float Ws[96 * 27];
    for (int i = threadIdx.x; i < 96 * 27; i += blockDim.x) Ws[i] = lw2[i];
    __syncthreads();
    int idx = blockIdx.x * blockDim.x + threadIdx.x;
    if (idx >= G * 27) return;
    int g = idx / 27;
    int c = idx - g * 27;
    const float* yr = y1 + (long long)g * 96;
    float acc = lb2[c];
#pragma unroll
    for (int k4 = 0; k4 < 24; ++k4) {
        float4 yv = *reinterpret_cast<const float4*>(yr + 4 * k4);
        acc += yv.x * Ws[(4 * k4 + 0) * 27 + c];
        acc += yv.y * Ws[(4 * k4 + 1) * 27 + c];
        acc += yv.z * Ws[(4 * k4 + 2) * 27 + c];
        acc += yv.w * Ws[(4 * k4 + 3) * 27 + c];
    }
    out[idx] = fmaxf(acc, 0.0f);
}

// ===================== launch =====================

extern "C" void kernel_launch(void* const* d_in, const int* in_sizes, int n_in,
                              void* d_out, int out_size, void* d_ws, size_t ws_size,
                              hipStream_t stream) {
    const float* x     = (const float*)d_in[0];
    const int*   ei    = (const int*)d_in[1];
    const int*   batch = (const int*)d_in[2];
    const float* W1  = (const float*)d_in[4];
    const float* b1  = (const float*)d_in[5];
    const float* W2  = (const float*)d_in[6];
    const float* b2  = (const float*)d_in[7];
    const float* W3  = (const float*)d_in[8];
    const float* b3  = (const float*)d_in[9];
    const float* W4  = (const float*)d_in[10];
    const float* b4  = (const float*)d_in[11];
    const float* lw1 = (const float*)d_in[12];
    const float* lb1 = (const float*)d_in[13];
    const float* lw2 = (const float*)d_in[14];
    const float* lb2 = (const float*)d_in[15];
    float* out = (float*)d_out;

    const int N = in_sizes[0] / 75;
    const int E = in_sizes[1] / 2;
    const int G = out_size / 27;
    const int* srcp = ei;
    const int* dstp = ei + E;

    char* ws = (char*)d_ws;
    size_t off = 0;
    auto carve = [&](size_t bytes) -> char* {
        char* p = ws + off;
        off = (off + bytes + 255) & ~(size_t)255;
        return p;
    };
    int*    row_ptr    = (int*)carve((size_t)(N + 1) * 4);
    int*    sorted_src = (int*)carve((size_t)E * 4);
    int*    seg        = (int*)carve((size_t)(G + 1) * 4);
    float*  dinv       = (float*)carve((size_t)N * 4);
    char*   Abuf       = carve((size_t)N * 36 * 4);   // also ebuf (E*4 = 16MB)
    char*   Bbuf       = carve((size_t)N * 36 * 4);   // also HB (~1MB)
    float*  pooled     = (float*)carve((size_t)G * 36 * 4);
    float*  y1         = (float*)carve((size_t)G * 96 * 4);
    (void)ws_size; (void)n_in;

    const int BLK = 256;
    const int nblk = cdiv(E, BUK_EDGES);
    int shift = 0;
    while (((long long)(N - 1) >> shift) >= NBUK) ++shift;  // N=1e6 -> 12 (npb=4096)

    int* ebuf = (int*)Abuf;
    int* HB   = (int*)Bbuf;

    // ---- edge bucketing: count -> colscan -> scatter (packed 32-bit entries) ----
    buk_count_kernel<<<nblk, NBUK, 0, stream>>>(dstp, HB, E, shift);
    buk_colscan_kernel<<<1, 1024, 0, stream>>>(HB, nblk);
    buk_scatter_kernel<<<nblk, NBUK, 0, stream>>>(srcp, dstp, HB, ebuf, E, shift);

    // ---- fused per-bucket CSR build (no global atomics) ----
    bucket_csr_kernel<<<NBUK, 256, 0, stream>>>(ebuf, HB, row_ptr, dinv, sorted_src, N, E, shift);
    segstart_kernel<<<cdiv(G + 1, BLK), BLK, 0, stream>>>(batch, seg, N, G);

    // fp16 u strides (halves): u1=16 (32B), u2=32 (64B line), u3=32 (64B line), u4=40 (80B)
    __half* u1 = (__half*)Bbuf;   // HB dead after bucket_csr
    __half* u2 = (__half*)Abuf;   // ebuf dead after bucket_csr
    __half* u3 = (__half*)Bbuf;
    __half* u4 = (__half*)Abuf;
    __half* h4 = (__half*)Bbuf;   // stride H4S=40 halves

    gemm_scale_kernel<75, 15, 16><<<cdiv(N, BLK), BLK, 0, stream>>>(x, W1, dinv, u1, N);
    agg_gemm_kernel<16, 15, 20, 32><<<cdiv(N, BLK), BLK, 0, stream>>>(u1, row_ptr, sorted_src, dinv, b1, W2, u2, N);
    agg_gemm_kernel<32, 20, 27, 32><<<cdiv(N, BLK), BLK, 0, stream>>>(u2, row_ptr, sorted_src, dinv, b2, W3, u3, N);
    agg_gemm_kernel<32, 27, 36, 40><<<cdiv(N, BLK), BLK, 0, stream>>>(u3, row_ptr, sorted_src, dinv, b3, W4, u4, N);
    agg_selu_kernel<40, 36, H4S><<<cdiv(N, BLK), BLK, 0, stream>>>(u4, row_ptr, sorted_src, dinv, b4, h4, N);

    // ---- pool: segmented sum over fp16 h4 ----
    pool_kernel_h<<<cdiv((long long)G * 9, BLK), BLK, 0, stream>>>(h4, seg, pooled, G);

    // ---- MLP head ----
    mlp1_kernel<<<cdiv((long long)G * 96, BLK), BLK, 0, stream>>>(pooled, lw1, lb1, y1, G);
    mlp2_kernel<<<cdiv((long long)G * 27, BLK), BLK, 0, stream>>>(y1, lw2, lb2, out, G);
}